// Round 13
// baseline (219.656 us; speedup 1.0000x reference)
//
#include <hip/hip_runtime.h>
#include <cmath>

namespace {
constexpr int H = 256, W = 256, HWp = H * W;
constexpr size_t PLANE = (size_t)4 * HWp * 64 * 2;  // one NHWC fp16 tensor, bytes
constexpr size_t NEED_FAST = 73728 + 3 * PLANE;     // w1tb | Xt_r | Xt_i | act
}

typedef _Float16 f16;
typedef unsigned int u32;
typedef __attribute__((ext_vector_type(4))) _Float16 f16x4;
typedef __attribute__((ext_vector_type(8))) _Float16 f16x8;
typedef __attribute__((ext_vector_type(4))) float f32x4;
typedef __attribute__((ext_vector_type(4))) unsigned int u32x4;

__device__ __forceinline__ void dma16(const char* g, char* l) {
    __builtin_amdgcn_global_load_lds(
        (const __attribute__((address_space(1))) u32*)g,
        (__attribute__((address_space(3))) u32*)l, 16, 0, 0);
}

// K_xt2: NCHW fp32 -> NHWC fp16 for both tensors; last y-slice does the
// weight transform w1 [co][ci][3][3] fp32 -> w1tb [k9][co][ci] fp16.
__global__ __launch_bounds__(256) void k_xt2(const float* __restrict__ zr,
                                             const float* __restrict__ zi,
                                             f16* __restrict__ Xt_r,
                                             f16* __restrict__ Xt_i,
                                             const float* __restrict__ w1,
                                             f16* __restrict__ w1tb,
                                             int ny_xt) {
    if ((int)blockIdx.y == ny_xt) {           // weight-transform slice
        int i = blockIdx.x * 256 + threadIdx.x;
        if (i < 64 * 576) {
            int co = i / 576, r = i - co * 576;
            int ci = r / 9, k9 = r - ci * 9;
            w1tb[(k9 * 64 + co) * 64 + ci] = (f16)w1[i];
        }
        return;
    }
    __shared__ f16 tile[64][80];
    const int t = threadIdx.x;
    const int p0 = blockIdx.x * 64;
    const int bb = blockIdx.y & 3;
    const bool im = blockIdx.y >= 4;
    const float* x = im ? zi : zr;
    f16* dst = im ? Xt_i : Xt_r;
    const size_t base = (size_t)bb * 64 * HWp;
#pragma unroll
    for (int r = 0; r < 4; ++r) {
        int q = r * 256 + t;
        int ci = q >> 4, px4 = (q & 15) * 4;
        f32x4 v = *reinterpret_cast<const f32x4*>(x + base + (size_t)ci * HWp + p0 + px4);
#pragma unroll
        for (int j = 0; j < 4; ++j) tile[px4 + j][ci] = (f16)v[j];
    }
    __syncthreads();
    const int px = t >> 2, q = t & 3;
    u32x4* d = reinterpret_cast<u32x4*>(dst + ((size_t)bb * HWp + p0 + px) * 64 + q * 16);
    const u32x4* s = reinterpret_cast<const u32x4*>(&tile[px][q * 16]);
    d[0] = s[0];
    d[1] = s[1];
}

// K1 v6: conv1, row-marching ring (proven R11).
__global__ __launch_bounds__(512, 1) void k_conv1(
        const f16* __restrict__ Xt, const f16* __restrict__ w1tb,
        const float* __restrict__ b1, f16* __restrict__ act) {
    __shared__ __align__(16) char lds[131072];

    const int tid = threadIdx.x;
    const int lane = tid & 63, wid = tid >> 6;
    const int lr = lane & 15, lg = lane >> 4;
    const int pg = wid & 3, cg = wid >> 2;

    const int bid = blockIdx.x;
    const int swz = (bid & 7) * 32 + (bid >> 3);
    const int b = swz >> 6;
    const int y0 = (swz & 63) * 4;

    const int swzb = (lane ^ ((lane >> 3) & 7)) << 4;
    const size_t img = (size_t)b * 256;

    f16x8 Wreg[9][2][2];
#pragma unroll
    for (int k9 = 0; k9 < 9; ++k9)
#pragma unroll
        for (int n = 0; n < 2; ++n)
#pragma unroll
            for (int c = 0; c < 2; ++c)
                Wreg[k9][n][c] = *reinterpret_cast<const f16x8*>(
                    w1tb + (size_t)(k9 * 64 + cg * 32 + n * 16 + lr) * 64
                         + c * 32 + lg * 8);

    float bias[2][4];
#pragma unroll
    for (int n = 0; n < 2; ++n) {
        f32x4 bv = *reinterpret_cast<const f32x4*>(b1 + cg * 32 + n * 16 + lg * 4);
#pragma unroll
        for (int r = 0; r < 4; ++r) bias[n][r] = bv[r];
    }

    auto stage = [&](int yy) {
        const char* src = (const char*)Xt + ((img + yy) * 256) * 128 + swzb;
        char* dst = lds + (yy & 3) * 32768;
#pragma unroll
        for (int i = 0; i < 4; ++i) {
            const int ch = wid + i * 8;
            dma16(src + ch * 1024, dst + ch * 1024);
        }
    };

    if (y0 > 0) stage(y0 - 1);
    stage(y0);
    stage(y0 + 1);
    __syncthreads();

    const f16x8 zf = (f16x8)(f16)0.f;

    for (int r = 0; r < 4; ++r) {
        const int y = y0 + r;
        const int yn = y + 2;
        if (r < 3 && yn < 256) stage(yn);

        f32x4 acc[4][2];
#pragma unroll
        for (int m = 0; m < 4; ++m)
#pragma unroll
            for (int n = 0; n < 2; ++n) acc[m][n] = (f32x4)0.f;

#pragma unroll
        for (int dyi = 0; dyi < 3; ++dyi) {
            const int yy = y + dyi - 1;
            if ((unsigned)yy >= 256u) continue;
            const char* sb = lds + (yy & 3) * 32768;
#pragma unroll
            for (int kx = 0; kx < 3; ++kx) {
                const int dx = kx - 1;
                const int px1 = pg * 64 + 16 + lr + dx;
                const bool ok0 = (unsigned)(px1 - 16) < 256u;
                const bool ok3 = (unsigned)(px1 + 32) < 256u;
                const int px0 = ok0 ? px1 - 16 : px1 - 16 - dx;
                const int px2 = px1 + 16;
                const int px3 = ok3 ? px1 + 32 : px1 + 32 - dx;
                const int k9 = dyi * 3 + kx;
#pragma unroll
                for (int c = 0; c < 2; ++c) {
                    const int pe = c * 4 + lg;
                    f16x8 A0 = *(const f16x8*)(sb + (px0 << 7) + ((pe ^ (px0 & 7)) << 4));
                    f16x8 A1 = *(const f16x8*)(sb + (px1 << 7) + ((pe ^ (px1 & 7)) << 4));
                    f16x8 A2 = *(const f16x8*)(sb + (px2 << 7) + ((pe ^ (px2 & 7)) << 4));
                    f16x8 A3 = *(const f16x8*)(sb + (px3 << 7) + ((pe ^ (px3 & 7)) << 4));
                    A0 = ok0 ? A0 : zf;
                    A3 = ok3 ? A3 : zf;
                    const f16x8 W0 = Wreg[k9][0][c];
                    const f16x8 W1 = Wreg[k9][1][c];
                    acc[0][0] = __builtin_amdgcn_mfma_f32_16x16x32_f16(W0, A0, acc[0][0], 0, 0, 0);
                    acc[0][1] = __builtin_amdgcn_mfma_f32_16x16x32_f16(W1, A0, acc[0][1], 0, 0, 0);
                    acc[1][0] = __builtin_amdgcn_mfma_f32_16x16x32_f16(W0, A1, acc[1][0], 0, 0, 0);
                    acc[1][1] = __builtin_amdgcn_mfma_f32_16x16x32_f16(W1, A1, acc[1][1], 0, 0, 0);
                    acc[2][0] = __builtin_amdgcn_mfma_f32_16x16x32_f16(W0, A2, acc[2][0], 0, 0, 0);
                    acc[2][1] = __builtin_amdgcn_mfma_f32_16x16x32_f16(W1, A2, acc[2][1], 0, 0, 0);
                    acc[3][0] = __builtin_amdgcn_mfma_f32_16x16x32_f16(W0, A3, acc[3][0], 0, 0, 0);
                    acc[3][1] = __builtin_amdgcn_mfma_f32_16x16x32_f16(W1, A3, acc[3][1], 0, 0, 0);
                }
            }
        }

        const size_t rb = (img + y) * 256;
#pragma unroll
        for (int m = 0; m < 4; ++m) {
            f16* ap = act + (rb + pg * 64 + m * 16 + lr) * 64 + cg * 32 + lg * 4;
#pragma unroll
            for (int n = 0; n < 2; ++n) {
                f16x4 o;
#pragma unroll
                for (int q = 0; q < 4; ++q) {
                    float v = acc[m][n][q] + bias[n][q];
                    v = v / (1.f + __expf(-v));
                    o[q] = (f16)v;
                }
                *reinterpret_cast<f16x4*>(ap + n * 16) = o;
            }
        }
        __syncthreads();
    }
}

// K2 (fallback path only): conv2 (64->1) + *dt -> psi.
__global__ __launch_bounds__(256) void k_conv2(
        const f16* __restrict__ act, const float* __restrict__ w2,
        const float* __restrict__ b2, const float* __restrict__ dtp,
        float* __restrict__ psi) {
    const int tx = threadIdx.x & 31, ty = threadIdx.x >> 5;
    const int px = blockIdx.x * 32 + tx;
    const int py = blockIdx.y * 8 + ty;
    const int b = blockIdx.z;

    float a0 = 0.f, a1 = 0.f, a2 = 0.f, a3 = 0.f;
#pragma unroll
    for (int dy = -1; dy <= 1; ++dy) {
        const int yy = py + dy;
        if ((unsigned)yy >= (unsigned)H) continue;
#pragma unroll
        for (int dx = -1; dx <= 1; ++dx) {
            const int xx = px + dx;
            const int k9 = (dy + 1) * 3 + (dx + 1);
            if ((unsigned)xx < (unsigned)W) {
                const f16x8* ap = reinterpret_cast<const f16x8*>(
                    act + (((size_t)b * H + yy) * W + xx) * 64);
                const float* wp = w2 + k9;
#pragma unroll
                for (int g = 0; g < 8; ++g) {
                    const f16x8 v = ap[g];
                    const int cb = g * 8;
                    a0 = fmaf((float)v[0], wp[(cb + 0) * 9], a0);
                    a1 = fmaf((float)v[1], wp[(cb + 1) * 9], a1);
                    a2 = fmaf((float)v[2], wp[(cb + 2) * 9], a2);
                    a3 = fmaf((float)v[3], wp[(cb + 3) * 9], a3);
                    a0 = fmaf((float)v[4], wp[(cb + 4) * 9], a0);
                    a1 = fmaf((float)v[5], wp[(cb + 5) * 9], a1);
                    a2 = fmaf((float)v[6], wp[(cb + 6) * 9], a2);
                    a3 = fmaf((float)v[7], wp[(cb + 7) * 9], a3);
                }
            }
        }
    }
    psi[((size_t)b * H + py) * W + px] = ((a0 + a1) + (a2 + a3) + b2[0]) * dtp[0];
}

// K_psam: fused conv2 + curl + bilinear sample (act now in d_ws -> no alias
// with out). Block = 1 row-half (128 px) x ALL 128 channels.
__global__ __launch_bounds__(256, 4) void k_psam(
        const f16* __restrict__ act, const float* __restrict__ w2,
        const float* __restrict__ b2, const float* __restrict__ dtp,
        const f16* __restrict__ Xt_r, const f16* __restrict__ Xt_i,
        float* __restrict__ out) {
    __shared__ float psi_s[3][132];
    __shared__ int   s_off[4][128];
    __shared__ float s_w[4][128];
    __shared__ __align__(16) float s_stage[64][132];

    const int tid = threadIdx.x;
    const int bid = blockIdx.x;                  // 0..2047
    const int swz = (bid & 7) * 256 + (bid >> 3);
    const int seg = swz & 1, y = (swz >> 1) & 255, b = swz >> 9;
    const int x0 = seg * 128;

    // Phase 0: psi window rows clamp(y-1..y+1), cols clamp(x0-1..x0+128).
    const float dtv = dtp[0], b2v = b2[0];
    for (int e = tid; e < 390; e += 256) {
        const int ry = e / 130, rx = e - ry * 130;
        const int yy = min(max(y - 1 + ry, 0), H - 1);
        const int xx = min(max(x0 - 1 + rx, 0), W - 1);
        float a0 = 0.f, a1 = 0.f, a2 = 0.f, a3 = 0.f;
#pragma unroll
        for (int dy = -1; dy <= 1; ++dy) {
            const int qy = yy + dy;
            if ((unsigned)qy >= (unsigned)H) continue;
#pragma unroll
            for (int dx = -1; dx <= 1; ++dx) {
                const int qx = xx + dx;
                const int k9 = (dy + 1) * 3 + (dx + 1);
                if ((unsigned)qx < (unsigned)W) {
                    const f16x8* ap = reinterpret_cast<const f16x8*>(
                        act + (((size_t)b * H + qy) * W + qx) * 64);
                    const float* wp = w2 + k9;
#pragma unroll
                    for (int g = 0; g < 8; ++g) {
                        const f16x8 v = ap[g];
                        const int cb = g * 8;
                        a0 = fmaf((float)v[0], wp[(cb + 0) * 9], a0);
                        a1 = fmaf((float)v[1], wp[(cb + 1) * 9], a1);
                        a2 = fmaf((float)v[2], wp[(cb + 2) * 9], a2);
                        a3 = fmaf((float)v[3], wp[(cb + 3) * 9], a3);
                        a0 = fmaf((float)v[4], wp[(cb + 4) * 9], a0);
                        a1 = fmaf((float)v[5], wp[(cb + 5) * 9], a1);
                        a2 = fmaf((float)v[6], wp[(cb + 6) * 9], a2);
                        a3 = fmaf((float)v[7], wp[(cb + 7) * 9], a3);
                    }
                }
            }
        }
        psi_s[ry][rx] = ((a0 + a1) + (a2 + a3) + b2v) * dtv;
    }
    __syncthreads();

    // Phase A: flow + gather setup (psi from LDS window).
    if (tid < 128) {
        const int px = x0 + tid;
        const float u = 0.5f * (psi_s[2][tid + 1] - psi_s[0][tid + 1]);
        const float v = -0.5f * (psi_s[1][tid + 2] - psi_s[1][tid]);
        const float gx = (-1.f + 2.f * px / (float)(W - 1)) - u * (2.f / (float)W);
        const float gy = (-1.f + 2.f * y / (float)(H - 1)) - v * (2.f / (float)H);
        float ix = fminf(fmaxf((gx + 1.f) * 0.5f * (float)(W - 1), 0.f), (float)(W - 1));
        float iy = fminf(fmaxf((gy + 1.f) * 0.5f * (float)(H - 1), 0.f), (float)(H - 1));
        const float xf = floorf(ix), yf = floorf(iy);
        const float wx = ix - xf, wy = iy - yf;
        const int ix0 = (int)xf, iy0 = (int)yf;
        const int ix1 = min(ix0 + 1, W - 1), iy1 = min(iy0 + 1, H - 1);
        s_off[0][tid] = (iy0 * W + ix0) * 128;
        s_off[1][tid] = (iy0 * W + ix1) * 128;
        s_off[2][tid] = (iy1 * W + ix0) * 128;
        s_off[3][tid] = (iy1 * W + ix1) * 128;
        s_w[0][tid] = (1.f - wx) * (1.f - wy);
        s_w[1][tid] = wx * (1.f - wy);
        s_w[2][tid] = (1.f - wx) * wy;
        s_w[3][tid] = wx * wy;
    }
    __syncthreads();

    const int p = tid >> 1, s = tid & 1;
    const int o0 = s_off[0][p], o1 = s_off[1][p], o2 = s_off[2][p], o3 = s_off[3][p];
    const float w0 = s_w[0][p], w1 = s_w[1][p], w2v = s_w[2][p], w3 = s_w[3][p];
    const int cl = tid >> 5;
    const int pxq = (tid & 31) * 4;
    const size_t obase = (size_t)b * 128 * HWp + (size_t)y * W + x0 + pxq;

#pragma unroll
    for (int pl = 0; pl < 2; ++pl) {
        const char* base = (const char*)(pl ? Xt_i : Xt_r)
                         + (size_t)b * HWp * 128 + s * 64;
        const char* c0 = base + o0;
        const char* c1 = base + o1;
        const char* c2 = base + o2;
        const char* c3 = base + o3;
        f16x8 h00 = *(const f16x8*)(c0);      f16x8 h01 = *(const f16x8*)(c0 + 16);
        f16x8 h02 = *(const f16x8*)(c0 + 32); f16x8 h03 = *(const f16x8*)(c0 + 48);
        f16x8 h10 = *(const f16x8*)(c1);      f16x8 h11 = *(const f16x8*)(c1 + 16);
        f16x8 h12 = *(const f16x8*)(c1 + 32); f16x8 h13 = *(const f16x8*)(c1 + 48);
        f16x8 h20 = *(const f16x8*)(c2);      f16x8 h21 = *(const f16x8*)(c2 + 16);
        f16x8 h22 = *(const f16x8*)(c2 + 32); f16x8 h23 = *(const f16x8*)(c2 + 48);
        f16x8 h30 = *(const f16x8*)(c3);      f16x8 h31 = *(const f16x8*)(c3 + 16);
        f16x8 h32 = *(const f16x8*)(c3 + 32); f16x8 h33 = *(const f16x8*)(c3 + 48);

        const int rb = s << 5;
#pragma unroll
        for (int k = 0; k < 8; ++k) {
            s_stage[rb + k][p] = w0 * (float)h00[k] + w1 * (float)h10[k]
                               + w2v * (float)h20[k] + w3 * (float)h30[k];
            s_stage[rb + 8 + k][p] = w0 * (float)h01[k] + w1 * (float)h11[k]
                                   + w2v * (float)h21[k] + w3 * (float)h31[k];
            s_stage[rb + 16 + k][p] = w0 * (float)h02[k] + w1 * (float)h12[k]
                                    + w2v * (float)h22[k] + w3 * (float)h32[k];
            s_stage[rb + 24 + k][p] = w0 * (float)h03[k] + w1 * (float)h13[k]
                                    + w2v * (float)h23[k] + w3 * (float)h33[k];
        }
        __syncthreads();
#pragma unroll
        for (int k = 0; k < 8; ++k) {
            const int c = cl + (k << 3);
            f32x4 vv = *(const f32x4*)&s_stage[c][pxq];
            *(f32x4*)(out + obase + (size_t)(pl * 64 + c) * HWp) = vv;
        }
        __syncthreads();
    }
}

// K3 fallback: scalar gather from fp32 NCHW.
__global__ __launch_bounds__(256) void k_sample_fb(
        const float* __restrict__ zr, const float* __restrict__ zi,
        const float* __restrict__ psi, float* __restrict__ out) {
    const int tx = threadIdx.x & 31, ty = threadIdx.x >> 5;
    const int px = blockIdx.x * 32 + tx;
    const int py = blockIdx.y * 8 + ty;
    const int b  = blockIdx.z >> 3;
    const int c0 = (blockIdx.z & 7) * 16;

    const float* pb = psi + b * HWp;
    const int yp = min(py + 1, H - 1), ym = max(py - 1, 0);
    const int xp = min(px + 1, W - 1), xm = max(px - 1, 0);
    const float u = 0.5f * (pb[yp * W + px] - pb[ym * W + px]);
    const float v = -0.5f * (pb[py * W + xp] - pb[py * W + xm]);

    const float gx = (-1.f + 2.f * px / (float)(W - 1)) - u * (2.f / (float)W);
    const float gy = (-1.f + 2.f * py / (float)(H - 1)) - v * (2.f / (float)H);

    float ix = fminf(fmaxf((gx + 1.f) * 0.5f * (float)(W - 1), 0.f), (float)(W - 1));
    float iy = fminf(fmaxf((gy + 1.f) * 0.5f * (float)(H - 1), 0.f), (float)(H - 1));
    const float xf = floorf(ix), yf = floorf(iy);
    const float wx = ix - xf, wy = iy - yf;
    const int ix0 = (int)xf, iy0 = (int)yf;
    const int ix1 = min(ix0 + 1, W - 1), iy1 = min(iy0 + 1, H - 1);

    const int o00 = iy0 * W + ix0, o01 = iy0 * W + ix1;
    const int o10 = iy1 * W + ix0, o11 = iy1 * W + ix1;
    const float w00 = (1.f - wx) * (1.f - wy), w01 = wx * (1.f - wy);
    const float w10 = (1.f - wx) * wy, w11 = wx * wy;

    const float* src0 = (c0 < 64) ? (zr + (size_t)b * 64 * HWp + (size_t)c0 * HWp)
                                  : (zi + (size_t)b * 64 * HWp + (size_t)(c0 - 64) * HWp);
    float* ob = out + ((size_t)b * 128 + c0) * HWp + py * W + px;
#pragma unroll
    for (int c = 0; c < 16; ++c) {
        const float* p = src0 + (size_t)c * HWp;
        ob[(size_t)c * HWp] = p[o00] * w00 + p[o01] * w01 + p[o10] * w10 + p[o11] * w11;
    }
}

extern "C" void kernel_launch(void* const* d_in, const int* in_sizes, int n_in,
                              void* d_out, int out_size, void* d_ws, size_t ws_size,
                              hipStream_t stream) {
    const float* z_real = (const float*)d_in[0];
    const float* z_imag = (const float*)d_in[1];
    const float* dt     = (const float*)d_in[2];
    const float* w1     = (const float*)d_in[3];
    const float* b1     = (const float*)d_in[4];
    const float* w2     = (const float*)d_in[5];
    const float* b2     = (const float*)d_in[6];

    float* out = (float*)d_out;
    char* ws = (char*)d_ws;
    f16* w1tb = (f16*)ws;                       // 73728 B

    if (ws_size >= NEED_FAST) {
        // ws layout: w1tb | Xt_r | Xt_i | act  — act no longer aliases out.
        f16* Xt_r = (f16*)(ws + 73728);
        f16* Xt_i = (f16*)(ws + 73728 + PLANE);
        f16* act  = (f16*)(ws + 73728 + 2 * PLANE);

        hipLaunchKernelGGL(k_xt2, dim3(HWp / 64, 9), dim3(256), 0, stream,
                           z_real, z_imag, Xt_r, Xt_i, w1, w1tb, 8);
        hipLaunchKernelGGL(k_conv1, dim3(256), dim3(512), 0, stream, Xt_r, w1tb, b1, act);
        hipLaunchKernelGGL(k_psam, dim3(2048), dim3(256), 0, stream,
                           act, w2, b2, dt, Xt_r, Xt_i, out);
    } else {
        float* psi = (float*)(ws + 73728);
        f16* Xt  = (f16*)((char*)d_out + 4096);
        f16* act = (f16*)((char*)d_out + 4096 + PLANE);

        hipLaunchKernelGGL(k_xt2, dim3(HWp / 64, 5), dim3(256), 0, stream,
                           z_real, z_real, Xt, Xt, w1, w1tb, 4);
        hipLaunchKernelGGL(k_conv1, dim3(256), dim3(512), 0, stream, Xt, w1tb, b1, act);
        hipLaunchKernelGGL(k_conv2, dim3(8, 32, 4), dim3(256), 0, stream, act, w2, b2, dt, psi);
        hipLaunchKernelGGL(k_sample_fb, dim3(8, 32, 32), dim3(256), 0, stream,
                           z_real, z_imag, psi, out);
    }
}

// Round 14
// 174.245 us; speedup vs baseline: 1.2606x; 1.2606x over previous
//
#include <hip/hip_runtime.h>
#include <cmath>

namespace {
constexpr int H = 256, W = 256, HWp = H * W;
constexpr size_t PLANE = (size_t)4 * HWp * 64 * 2;  // one NHWC fp16 tensor, bytes
constexpr size_t NEED_FAST = 73728 + 2 * PLANE + (1u << 20);
}

typedef _Float16 f16;
typedef unsigned int u32;
typedef __attribute__((ext_vector_type(4))) _Float16 f16x4;
typedef __attribute__((ext_vector_type(8))) _Float16 f16x8;
typedef __attribute__((ext_vector_type(4))) float f32x4;
typedef __attribute__((ext_vector_type(4))) unsigned int u32x4;

__device__ __forceinline__ void dma16(const char* g, char* l) {
    __builtin_amdgcn_global_load_lds(
        (const __attribute__((address_space(1))) u32*)g,
        (__attribute__((address_space(3))) u32*)l, 16, 0, 0);
}

// K_xt2: NCHW fp32 -> NHWC fp16 for both tensors; last y-slice does the
// weight transform w1 [co][ci][3][3] fp32 -> w1tb [k9][co][ci] fp16.
__global__ __launch_bounds__(256) void k_xt2(const float* __restrict__ zr,
                                             const float* __restrict__ zi,
                                             f16* __restrict__ Xt_r,
                                             f16* __restrict__ Xt_i,
                                             const float* __restrict__ w1,
                                             f16* __restrict__ w1tb,
                                             int ny_xt) {
    if ((int)blockIdx.y == ny_xt) {
        int i = blockIdx.x * 256 + threadIdx.x;
        if (i < 64 * 576) {
            int co = i / 576, r = i - co * 576;
            int ci = r / 9, k9 = r - ci * 9;
            w1tb[(k9 * 64 + co) * 64 + ci] = (f16)w1[i];
        }
        return;
    }
    __shared__ f16 tile[64][80];
    const int t = threadIdx.x;
    const int p0 = blockIdx.x * 64;
    const int bb = blockIdx.y & 3;
    const bool im = blockIdx.y >= 4;
    const float* x = im ? zi : zr;
    f16* dst = im ? Xt_i : Xt_r;
    const size_t base = (size_t)bb * 64 * HWp;
#pragma unroll
    for (int r = 0; r < 4; ++r) {
        int q = r * 256 + t;
        int ci = q >> 4, px4 = (q & 15) * 4;
        f32x4 v = *reinterpret_cast<const f32x4*>(x + base + (size_t)ci * HWp + p0 + px4);
#pragma unroll
        for (int j = 0; j < 4; ++j) tile[px4 + j][ci] = (f16)v[j];
    }
    __syncthreads();
    const int px = t >> 2, q = t & 3;
    u32x4* d = reinterpret_cast<u32x4*>(dst + ((size_t)bb * HWp + p0 + px) * 64 + q * 16);
    const u32x4* s = reinterpret_cast<const u32x4*>(&tile[px][q * 16]);
    d[0] = s[0];
    d[1] = s[1];
}

// K1 v7: conv1 row-marching ring, PAIRED output rows. Rows y,y+1 share
// panels: each fragment is loaded once and feeds both rows' accumulators
// (A-LDS reads -33%). 4-slot ring (128 KB); stage y+3,y+4 between pairs.
__global__ __launch_bounds__(512, 1) void k_conv1(
        const f16* __restrict__ Xt, const f16* __restrict__ w1tb,
        const float* __restrict__ b1, f16* __restrict__ act) {
    __shared__ __align__(16) char lds[131072];

    const int tid = threadIdx.x;
    const int lane = tid & 63, wid = tid >> 6;
    const int lr = lane & 15, lg = lane >> 4;
    const int pg = wid & 3, cg = wid >> 2;

    const int bid = blockIdx.x;
    const int swz = (bid & 7) * 32 + (bid >> 3);
    const int b = swz >> 6;
    const int y0 = (swz & 63) * 4;

    const int swzb = (lane ^ ((lane >> 3) & 7)) << 4;
    const size_t img = (size_t)b * 256;

    f16x8 Wreg[9][2][2];
#pragma unroll
    for (int k9 = 0; k9 < 9; ++k9)
#pragma unroll
        for (int n = 0; n < 2; ++n)
#pragma unroll
            for (int c = 0; c < 2; ++c)
                Wreg[k9][n][c] = *reinterpret_cast<const f16x8*>(
                    w1tb + (size_t)(k9 * 64 + cg * 32 + n * 16 + lr) * 64
                         + c * 32 + lg * 8);

    float bias[2][4];
#pragma unroll
    for (int n = 0; n < 2; ++n) {
        f32x4 bv = *reinterpret_cast<const f32x4*>(b1 + cg * 32 + n * 16 + lg * 4);
#pragma unroll
        for (int r = 0; r < 4; ++r) bias[n][r] = bv[r];
    }

    auto stage = [&](int yy) {
        const char* src = (const char*)Xt + ((img + yy) * 256) * 128 + swzb;
        char* dst = lds + (yy & 3) * 32768;
#pragma unroll
        for (int i = 0; i < 4; ++i) {
            const int ch = wid + i * 8;
            dma16(src + ch * 1024, dst + ch * 1024);
        }
    };

    if (y0 > 0) stage(y0 - 1);
    stage(y0);
    stage(y0 + 1);
    stage(y0 + 2);
    __syncthreads();

    const f16x8 zf = (f16x8)(f16)0.f;

#pragma unroll
    for (int pr = 0; pr < 2; ++pr) {
        const int y = y0 + pr * 2;                // pair: rows y, y+1

        f32x4 acc0[4][2], acc1[4][2];
#pragma unroll
        for (int m = 0; m < 4; ++m)
#pragma unroll
            for (int n = 0; n < 2; ++n) { acc0[m][n] = (f32x4)0.f; acc1[m][n] = (f32x4)0.f; }

#pragma unroll
        for (int pi = 0; pi < 4; ++pi) {          // panel yy = y-1+pi
            const int yy = y - 1 + pi;
            if ((unsigned)yy >= 256u) continue;   // uniform zero-pad skip
            const char* sb = lds + (yy & 3) * 32768;
#pragma unroll
            for (int kx = 0; kx < 3; ++kx) {
                const int dx = kx - 1;
                const int px1 = pg * 64 + 16 + lr + dx;
                const bool ok0 = (unsigned)(px1 - 16) < 256u;
                const bool ok3 = (unsigned)(px1 + 32) < 256u;
                const int px0 = ok0 ? px1 - 16 : px1 - 16 - dx;
                const int px2 = px1 + 16;
                const int px3 = ok3 ? px1 + 32 : px1 + 32 - dx;
#pragma unroll
                for (int c = 0; c < 2; ++c) {
                    const int pe = c * 4 + lg;
                    f16x8 A0 = *(const f16x8*)(sb + (px0 << 7) + ((pe ^ (px0 & 7)) << 4));
                    f16x8 A1 = *(const f16x8*)(sb + (px1 << 7) + ((pe ^ (px1 & 7)) << 4));
                    f16x8 A2 = *(const f16x8*)(sb + (px2 << 7) + ((pe ^ (px2 & 7)) << 4));
                    f16x8 A3 = *(const f16x8*)(sb + (px3 << 7) + ((pe ^ (px3 & 7)) << 4));
                    A0 = ok0 ? A0 : zf;
                    A3 = ok3 ? A3 : zf;
                    if (pi < 3) {                 // tap for row y (dyi = pi)
                        const int k9 = pi * 3 + kx;
                        const f16x8 W0 = Wreg[k9][0][c];
                        const f16x8 W1 = Wreg[k9][1][c];
                        acc0[0][0] = __builtin_amdgcn_mfma_f32_16x16x32_f16(W0, A0, acc0[0][0], 0, 0, 0);
                        acc0[0][1] = __builtin_amdgcn_mfma_f32_16x16x32_f16(W1, A0, acc0[0][1], 0, 0, 0);
                        acc0[1][0] = __builtin_amdgcn_mfma_f32_16x16x32_f16(W0, A1, acc0[1][0], 0, 0, 0);
                        acc0[1][1] = __builtin_amdgcn_mfma_f32_16x16x32_f16(W1, A1, acc0[1][1], 0, 0, 0);
                        acc0[2][0] = __builtin_amdgcn_mfma_f32_16x16x32_f16(W0, A2, acc0[2][0], 0, 0, 0);
                        acc0[2][1] = __builtin_amdgcn_mfma_f32_16x16x32_f16(W1, A2, acc0[2][1], 0, 0, 0);
                        acc0[3][0] = __builtin_amdgcn_mfma_f32_16x16x32_f16(W0, A3, acc0[3][0], 0, 0, 0);
                        acc0[3][1] = __builtin_amdgcn_mfma_f32_16x16x32_f16(W1, A3, acc0[3][1], 0, 0, 0);
                    }
                    if (pi > 0) {                 // tap for row y+1 (dyi = pi-1)
                        const int k9 = (pi - 1) * 3 + kx;
                        const f16x8 W0 = Wreg[k9][0][c];
                        const f16x8 W1 = Wreg[k9][1][c];
                        acc1[0][0] = __builtin_amdgcn_mfma_f32_16x16x32_f16(W0, A0, acc1[0][0], 0, 0, 0);
                        acc1[0][1] = __builtin_amdgcn_mfma_f32_16x16x32_f16(W1, A0, acc1[0][1], 0, 0, 0);
                        acc1[1][0] = __builtin_amdgcn_mfma_f32_16x16x32_f16(W0, A1, acc1[1][0], 0, 0, 0);
                        acc1[1][1] = __builtin_amdgcn_mfma_f32_16x16x32_f16(W1, A1, acc1[1][1], 0, 0, 0);
                        acc1[2][0] = __builtin_amdgcn_mfma_f32_16x16x32_f16(W0, A2, acc1[2][0], 0, 0, 0);
                        acc1[2][1] = __builtin_amdgcn_mfma_f32_16x16x32_f16(W1, A2, acc1[2][1], 0, 0, 0);
                        acc1[3][0] = __builtin_amdgcn_mfma_f32_16x16x32_f16(W0, A3, acc1[3][0], 0, 0, 0);
                        acc1[3][1] = __builtin_amdgcn_mfma_f32_16x16x32_f16(W1, A3, acc1[3][1], 0, 0, 0);
                    }
                }
            }
        }

        // epilogue rows y, y+1
#pragma unroll
        for (int rr = 0; rr < 2; ++rr) {
            const size_t rb = (img + y + rr) * 256;
#pragma unroll
            for (int m = 0; m < 4; ++m) {
                f16* ap = act + (rb + pg * 64 + m * 16 + lr) * 64 + cg * 32 + lg * 4;
#pragma unroll
                for (int n = 0; n < 2; ++n) {
                    const f32x4 a = rr ? acc1[m][n] : acc0[m][n];
                    f16x4 o;
#pragma unroll
                    for (int q = 0; q < 4; ++q) {
                        float v = a[q] + bias[n][q];
                        v = v / (1.f + __expf(-v));
                        o[q] = (f16)v;
                    }
                    *reinterpret_cast<f16x4*>(ap + n * 16) = o;
                }
            }
        }
        __syncthreads();                          // all reads of pair panels done
        if (pr == 0) {
            if (y0 + 3 < 256) stage(y0 + 3);      // slot (y0-1)&3, now free
            if (y0 + 4 < 256) stage(y0 + 4);      // slot  y0&3,    now free
            __syncthreads();                      // drain before pair 2
        }
    }
}

// K2: conv2 (64->1) + *dt -> psi. NHWC fp16 input, f16x8 vector loads.
__global__ __launch_bounds__(256) void k_conv2(
        const f16* __restrict__ act, const float* __restrict__ w2,
        const float* __restrict__ b2, const float* __restrict__ dtp,
        float* __restrict__ psi) {
    const int tx = threadIdx.x & 31, ty = threadIdx.x >> 5;
    const int px = blockIdx.x * 32 + tx;
    const int py = blockIdx.y * 8 + ty;
    const int b = blockIdx.z;

    float a0 = 0.f, a1 = 0.f, a2 = 0.f, a3 = 0.f;
#pragma unroll
    for (int dy = -1; dy <= 1; ++dy) {
        const int yy = py + dy;
        if ((unsigned)yy >= (unsigned)H) continue;
#pragma unroll
        for (int dx = -1; dx <= 1; ++dx) {
            const int xx = px + dx;
            const int k9 = (dy + 1) * 3 + (dx + 1);
            if ((unsigned)xx < (unsigned)W) {
                const f16x8* ap = reinterpret_cast<const f16x8*>(
                    act + (((size_t)b * H + yy) * W + xx) * 64);
                const float* wp = w2 + k9;
#pragma unroll
                for (int g = 0; g < 8; ++g) {
                    const f16x8 v = ap[g];
                    const int cb = g * 8;
                    a0 = fmaf((float)v[0], wp[(cb + 0) * 9], a0);
                    a1 = fmaf((float)v[1], wp[(cb + 1) * 9], a1);
                    a2 = fmaf((float)v[2], wp[(cb + 2) * 9], a2);
                    a3 = fmaf((float)v[3], wp[(cb + 3) * 9], a3);
                    a0 = fmaf((float)v[4], wp[(cb + 4) * 9], a0);
                    a1 = fmaf((float)v[5], wp[(cb + 5) * 9], a1);
                    a2 = fmaf((float)v[6], wp[(cb + 6) * 9], a2);
                    a3 = fmaf((float)v[7], wp[(cb + 7) * 9], a3);
                }
            }
        }
    }
    psi[((size_t)b * H + py) * W + px] = ((a0 + a1) + (a2 + a3) + b2[0]) * dtp[0];
}

// K3 v3: block = 1 row-half (128 px) x ALL 128 channels (proven R8/R11).
__global__ __launch_bounds__(256, 4) void k_sample3(
        const f16* __restrict__ Xt_r, const f16* __restrict__ Xt_i,
        const float* __restrict__ psi, float* __restrict__ out) {
    __shared__ int   s_off[4][128];
    __shared__ float s_w[4][128];
    __shared__ __align__(16) float s_stage[64][132];

    const int tid = threadIdx.x;
    const int bid = blockIdx.x;
    const int swz = (bid & 7) * 256 + (bid >> 3);
    const int seg = swz & 1, y = (swz >> 1) & 255, b = swz >> 9;
    const int x0 = seg * 128;

    if (tid < 128) {
        const int px = x0 + tid;
        const float* pb = psi + b * HWp;
        const int yp = min(y + 1, H - 1), ym = max(y - 1, 0);
        const int xp = min(px + 1, W - 1), xm = max(px - 1, 0);
        const float u = 0.5f * (pb[yp * W + px] - pb[ym * W + px]);
        const float v = -0.5f * (pb[y * W + xp] - pb[y * W + xm]);
        const float gx = (-1.f + 2.f * px / (float)(W - 1)) - u * (2.f / (float)W);
        const float gy = (-1.f + 2.f * y / (float)(H - 1)) - v * (2.f / (float)H);
        float ix = fminf(fmaxf((gx + 1.f) * 0.5f * (float)(W - 1), 0.f), (float)(W - 1));
        float iy = fminf(fmaxf((gy + 1.f) * 0.5f * (float)(H - 1), 0.f), (float)(H - 1));
        const float xf = floorf(ix), yf = floorf(iy);
        const float wx = ix - xf, wy = iy - yf;
        const int ix0 = (int)xf, iy0 = (int)yf;
        const int ix1 = min(ix0 + 1, W - 1), iy1 = min(iy0 + 1, H - 1);
        s_off[0][tid] = (iy0 * W + ix0) * 128;
        s_off[1][tid] = (iy0 * W + ix1) * 128;
        s_off[2][tid] = (iy1 * W + ix0) * 128;
        s_off[3][tid] = (iy1 * W + ix1) * 128;
        s_w[0][tid] = (1.f - wx) * (1.f - wy);
        s_w[1][tid] = wx * (1.f - wy);
        s_w[2][tid] = (1.f - wx) * wy;
        s_w[3][tid] = wx * wy;
    }
    __syncthreads();

    const int p = tid >> 1, s = tid & 1;
    const int o0 = s_off[0][p], o1 = s_off[1][p], o2 = s_off[2][p], o3 = s_off[3][p];
    const float w0 = s_w[0][p], w1 = s_w[1][p], w2 = s_w[2][p], w3 = s_w[3][p];
    const int cl = tid >> 5;
    const int pxq = (tid & 31) * 4;
    const size_t obase = (size_t)b * 128 * HWp + (size_t)y * W + x0 + pxq;

#pragma unroll
    for (int pl = 0; pl < 2; ++pl) {
        const char* base = (const char*)(pl ? Xt_i : Xt_r)
                         + (size_t)b * HWp * 128 + s * 64;
        const char* c0 = base + o0;
        const char* c1 = base + o1;
        const char* c2 = base + o2;
        const char* c3 = base + o3;
        f16x8 h00 = *(const f16x8*)(c0);      f16x8 h01 = *(const f16x8*)(c0 + 16);
        f16x8 h02 = *(const f16x8*)(c0 + 32); f16x8 h03 = *(const f16x8*)(c0 + 48);
        f16x8 h10 = *(const f16x8*)(c1);      f16x8 h11 = *(const f16x8*)(c1 + 16);
        f16x8 h12 = *(const f16x8*)(c1 + 32); f16x8 h13 = *(const f16x8*)(c1 + 48);
        f16x8 h20 = *(const f16x8*)(c2);      f16x8 h21 = *(const f16x8*)(c2 + 16);
        f16x8 h22 = *(const f16x8*)(c2 + 32); f16x8 h23 = *(const f16x8*)(c2 + 48);
        f16x8 h30 = *(const f16x8*)(c3);      f16x8 h31 = *(const f16x8*)(c3 + 16);
        f16x8 h32 = *(const f16x8*)(c3 + 32); f16x8 h33 = *(const f16x8*)(c3 + 48);

        const int rb = s << 5;
#pragma unroll
        for (int k = 0; k < 8; ++k) {
            s_stage[rb + k][p] = w0 * (float)h00[k] + w1 * (float)h10[k]
                               + w2 * (float)h20[k] + w3 * (float)h30[k];
            s_stage[rb + 8 + k][p] = w0 * (float)h01[k] + w1 * (float)h11[k]
                                   + w2 * (float)h21[k] + w3 * (float)h31[k];
            s_stage[rb + 16 + k][p] = w0 * (float)h02[k] + w1 * (float)h12[k]
                                    + w2 * (float)h22[k] + w3 * (float)h32[k];
            s_stage[rb + 24 + k][p] = w0 * (float)h03[k] + w1 * (float)h13[k]
                                    + w2 * (float)h23[k] + w3 * (float)h33[k];
        }
        __syncthreads();
#pragma unroll
        for (int k = 0; k < 8; ++k) {
            const int c = cl + (k << 3);
            f32x4 vv = *(const f32x4*)&s_stage[c][pxq];
            *(f32x4*)(out + obase + (size_t)(pl * 64 + c) * HWp) = vv;
        }
        __syncthreads();
    }
}

// K3 fallback: scalar gather from fp32 NCHW.
__global__ __launch_bounds__(256) void k_sample_fb(
        const float* __restrict__ zr, const float* __restrict__ zi,
        const float* __restrict__ psi, float* __restrict__ out) {
    const int tx = threadIdx.x & 31, ty = threadIdx.x >> 5;
    const int px = blockIdx.x * 32 + tx;
    const int py = blockIdx.y * 8 + ty;
    const int b  = blockIdx.z >> 3;
    const int c0 = (blockIdx.z & 7) * 16;

    const float* pb = psi + b * HWp;
    const int yp = min(py + 1, H - 1), ym = max(py - 1, 0);
    const int xp = min(px + 1, W - 1), xm = max(px - 1, 0);
    const float u = 0.5f * (pb[yp * W + px] - pb[ym * W + px]);
    const float v = -0.5f * (pb[py * W + xp] - pb[py * W + xm]);

    const float gx = (-1.f + 2.f * px / (float)(W - 1)) - u * (2.f / (float)W);
    const float gy = (-1.f + 2.f * py / (float)(H - 1)) - v * (2.f / (float)H);

    float ix = fminf(fmaxf((gx + 1.f) * 0.5f * (float)(W - 1), 0.f), (float)(W - 1));
    float iy = fminf(fmaxf((gy + 1.f) * 0.5f * (float)(H - 1), 0.f), (float)(H - 1));
    const float xf = floorf(ix), yf = floorf(iy);
    const float wx = ix - xf, wy = iy - yf;
    const int ix0 = (int)xf, iy0 = (int)yf;
    const int ix1 = min(ix0 + 1, W - 1), iy1 = min(iy0 + 1, H - 1);

    const int o00 = iy0 * W + ix0, o01 = iy0 * W + ix1;
    const int o10 = iy1 * W + ix0, o11 = iy1 * W + ix1;
    const float w00 = (1.f - wx) * (1.f - wy), w01 = wx * (1.f - wy);
    const float w10 = (1.f - wx) * wy, w11 = wx * wy;

    const float* src0 = (c0 < 64) ? (zr + (size_t)b * 64 * HWp + (size_t)c0 * HWp)
                                  : (zi + (size_t)b * 64 * HWp + (size_t)(c0 - 64) * HWp);
    float* ob = out + ((size_t)b * 128 + c0) * HWp + py * W + px;
#pragma unroll
    for (int c = 0; c < 16; ++c) {
        const float* p = src0 + (size_t)c * HWp;
        ob[(size_t)c * HWp] = p[o00] * w00 + p[o01] * w01 + p[o10] * w10 + p[o11] * w11;
    }
}

extern "C" void kernel_launch(void* const* d_in, const int* in_sizes, int n_in,
                              void* d_out, int out_size, void* d_ws, size_t ws_size,
                              hipStream_t stream) {
    const float* z_real = (const float*)d_in[0];
    const float* z_imag = (const float*)d_in[1];
    const float* dt     = (const float*)d_in[2];
    const float* w1     = (const float*)d_in[3];
    const float* b1     = (const float*)d_in[4];
    const float* w2     = (const float*)d_in[5];
    const float* b2     = (const float*)d_in[6];

    float* out = (float*)d_out;
    char* ws = (char*)d_ws;
    f16* w1tb = (f16*)ws;                       // 73728 B

    if (ws_size >= NEED_FAST) {
        // ws layout: w1tb | Xt_r | Xt_i | psi
        f16* Xt_r  = (f16*)(ws + 73728);
        f16* Xt_i  = (f16*)(ws + 73728 + PLANE);
        float* psi = (float*)(ws + 73728 + 2 * PLANE);
        f16* act   = (f16*)d_out;   // consumed by conv2 before sample3 overwrites

        hipLaunchKernelGGL(k_xt2, dim3(HWp / 64, 9), dim3(256), 0, stream,
                           z_real, z_imag, Xt_r, Xt_i, w1, w1tb, 8);
        hipLaunchKernelGGL(k_conv1, dim3(256), dim3(512), 0, stream, Xt_r, w1tb, b1, act);
        hipLaunchKernelGGL(k_conv2, dim3(8, 32, 4), dim3(256), 0, stream, act, w2, b2, dt, psi);
        hipLaunchKernelGGL(k_sample3, dim3(2048), dim3(256), 0, stream,
                           Xt_r, Xt_i, psi, out);
    } else {
        float* psi = (float*)(ws + 73728);
        f16* Xt  = (f16*)((char*)d_out + 4096);
        f16* act = (f16*)((char*)d_out + 4096 + PLANE);

        hipLaunchKernelGGL(k_xt2, dim3(HWp / 64, 5), dim3(256), 0, stream,
                           z_real, z_real, Xt, Xt, w1, w1tb, 4);
        hipLaunchKernelGGL(k_conv1, dim3(256), dim3(512), 0, stream, Xt, w1tb, b1, act);
        hipLaunchKernelGGL(k_conv2, dim3(8, 32, 4), dim3(256), 0, stream, act, w2, b2, dt, psi);
        hipLaunchKernelGGL(k_sample_fb, dim3(8, 32, 32), dim3(256), 0, stream,
                           z_real, z_imag, psi, out);
    }
}

// Round 15
// 162.243 us; speedup vs baseline: 1.3539x; 1.0740x over previous
//
#include <hip/hip_runtime.h>
#include <cmath>

namespace {
constexpr int H = 256, W = 256, HWp = H * W;
constexpr size_t PLANE = (size_t)4 * HWp * 64 * 2;  // one NHWC fp16 tensor, bytes
constexpr size_t NEED_FAST = 73728 + 2 * PLANE + (1u << 20);
}

typedef _Float16 f16;
typedef unsigned int u32;
typedef __attribute__((ext_vector_type(4))) _Float16 f16x4;
typedef __attribute__((ext_vector_type(8))) _Float16 f16x8;
typedef __attribute__((ext_vector_type(4))) float f32x4;
typedef __attribute__((ext_vector_type(4))) unsigned int u32x4;

__device__ __forceinline__ void dma16(const char* g, char* l) {
    __builtin_amdgcn_global_load_lds(
        (const __attribute__((address_space(1))) u32*)g,
        (__attribute__((address_space(3))) u32*)l, 16, 0, 0);
}

// K_xt2: NCHW fp32 -> NHWC fp16 for both tensors; last y-slice does the
// weight transform w1 [co][ci][3][3] fp32 -> w1tb [k9][co][ci] fp16.
__global__ __launch_bounds__(256) void k_xt2(const float* __restrict__ zr,
                                             const float* __restrict__ zi,
                                             f16* __restrict__ Xt_r,
                                             f16* __restrict__ Xt_i,
                                             const float* __restrict__ w1,
                                             f16* __restrict__ w1tb,
                                             int ny_xt) {
    if ((int)blockIdx.y == ny_xt) {
        int i = blockIdx.x * 256 + threadIdx.x;
        if (i < 64 * 576) {
            int co = i / 576, r = i - co * 576;
            int ci = r / 9, k9 = r - ci * 9;
            w1tb[(k9 * 64 + co) * 64 + ci] = (f16)w1[i];
        }
        return;
    }
    __shared__ f16 tile[64][80];
    const int t = threadIdx.x;
    const int p0 = blockIdx.x * 64;
    const int bb = blockIdx.y & 3;
    const bool im = blockIdx.y >= 4;
    const float* x = im ? zi : zr;
    f16* dst = im ? Xt_i : Xt_r;
    const size_t base = (size_t)bb * 64 * HWp;
#pragma unroll
    for (int r = 0; r < 4; ++r) {
        int q = r * 256 + t;
        int ci = q >> 4, px4 = (q & 15) * 4;
        f32x4 v = *reinterpret_cast<const f32x4*>(x + base + (size_t)ci * HWp + p0 + px4);
#pragma unroll
        for (int j = 0; j < 4; ++j) tile[px4 + j][ci] = (f16)v[j];
    }
    __syncthreads();
    const int px = t >> 2, q = t & 3;
    u32x4* d = reinterpret_cast<u32x4*>(dst + ((size_t)bb * HWp + p0 + px) * 64 + q * 16);
    const u32x4* s = reinterpret_cast<const u32x4*>(&tile[px][q * 16]);
    d[0] = s[0];
    d[1] = s[1];
}

// K1 v8: conv1 ring @ 2 blocks/CU. Block = 128-px segment x 64 co x 4 rows,
// 256 threads (2 px-groups x 2 co-groups). Ring = 4 slots x 18 KB (144-px
// halo rows, R7 staging). W in registers. One barrier per row; two resident
// blocks overlap each other's stage bubbles.
__global__ __launch_bounds__(256, 2) void k_conv1(
        const f16* __restrict__ Xt, const f16* __restrict__ w1tb,
        const float* __restrict__ b1, f16* __restrict__ act) {
    __shared__ __align__(16) char lds[73728];    // 4 ring slots x 18432 B

    const int tid = threadIdx.x;
    const int lane = tid & 63, wid = tid >> 6;
    const int lr = lane & 15, lg = lane >> 4;
    const int pg = wid & 1, cg = wid >> 1;       // 64-px group, 32-co group

    const int bid = blockIdx.x;                  // 0..511
    const int swz = (bid & 7) * 64 + (bid >> 3); // XCD-contiguous
    const int b = swz >> 7;
    const int y0 = ((swz >> 1) & 63) * 4;
    const int x0 = (swz & 1) << 7;

    const int swzb = (lane ^ ((lane >> 3) & 7)) << 4;
    const size_t img = (size_t)b * 256;

    f16x8 Wreg[9][2][2];
#pragma unroll
    for (int k9 = 0; k9 < 9; ++k9)
#pragma unroll
        for (int n = 0; n < 2; ++n)
#pragma unroll
            for (int c = 0; c < 2; ++c)
                Wreg[k9][n][c] = *reinterpret_cast<const f16x8*>(
                    w1tb + (size_t)(k9 * 64 + cg * 32 + n * 16 + lr) * 64
                         + c * 32 + lg * 8);

    float bias[2][4];
#pragma unroll
    for (int n = 0; n < 2; ++n) {
        f32x4 bv = *reinterpret_cast<const f32x4*>(b1 + cg * 32 + n * 16 + lg * 4);
#pragma unroll
        for (int r = 0; r < 4; ++r) bias[n][r] = bv[r];
    }

    // stage one 144-px halo row segment (18 KB) into ring slot yy&3.
    auto stage = [&](int yy) {
        const char* src = (const char*)Xt +
            ((((size_t)b * 256 + yy) * 256 + x0 - 8) * 128) + swzb;
        char* dst = lds + (yy & 3) * 18432;
#pragma unroll
        for (int i = 0; i < 5; ++i) {
            const int j = wid + i * 4;           // 18 chunks of 1 KB
            if (j < 18) dma16(src + j * 1024, dst + j * 1024);
        }
    };

    if (y0 > 0) stage(y0 - 1);
    stage(y0);
    stage(y0 + 1);
    __syncthreads();

    const f16x8 zf = (f16x8)(f16)0.f;

    for (int r = 0; r < 4; ++r) {
        const int y = y0 + r;
        const int yn = y + 2;
        if (r < 3 && yn < 256) stage(yn);        // slot (y+2)&3: disjoint

        f32x4 acc[4][2];
#pragma unroll
        for (int m = 0; m < 4; ++m)
#pragma unroll
            for (int n = 0; n < 2; ++n) acc[m][n] = (f32x4)0.f;

#pragma unroll
        for (int dyi = 0; dyi < 3; ++dyi) {
            const int yy = y + dyi - 1;
            if ((unsigned)yy >= 256u) continue;  // image-edge zero pad
            const char* sb = lds + (yy & 3) * 18432;
#pragma unroll
            for (int kx = 0; kx < 3; ++kx) {
                const int dx = kx - 1;
                const int gx0 = x0 + pg * 64 + lr + dx;          // m=0 pixel
                const bool ok0 = (unsigned)gx0 < 256u;           // left img edge
                const bool ok3 = (unsigned)(gx0 + 48) < 256u;    // right img edge
                const int loc1 = 8 + pg * 64 + 16 + lr + dx;     // m=1 local
                const int loc0 = ok0 ? loc1 - 16 : loc1 - 16 - dx;
                const int loc2 = loc1 + 16;
                const int loc3 = ok3 ? loc1 + 32 : loc1 + 32 - dx;
                const int k9 = dyi * 3 + kx;
#pragma unroll
                for (int c = 0; c < 2; ++c) {
                    const int pe = c * 4 + lg;
                    f16x8 A0 = *(const f16x8*)(sb + (loc0 << 7) + ((pe ^ (loc0 & 7)) << 4));
                    f16x8 A1 = *(const f16x8*)(sb + (loc1 << 7) + ((pe ^ (loc1 & 7)) << 4));
                    f16x8 A2 = *(const f16x8*)(sb + (loc2 << 7) + ((pe ^ (loc2 & 7)) << 4));
                    f16x8 A3 = *(const f16x8*)(sb + (loc3 << 7) + ((pe ^ (loc3 & 7)) << 4));
                    A0 = ok0 ? A0 : zf;
                    A3 = ok3 ? A3 : zf;
                    const f16x8 W0 = Wreg[k9][0][c];
                    const f16x8 W1 = Wreg[k9][1][c];
                    acc[0][0] = __builtin_amdgcn_mfma_f32_16x16x32_f16(W0, A0, acc[0][0], 0, 0, 0);
                    acc[0][1] = __builtin_amdgcn_mfma_f32_16x16x32_f16(W1, A0, acc[0][1], 0, 0, 0);
                    acc[1][0] = __builtin_amdgcn_mfma_f32_16x16x32_f16(W0, A1, acc[1][0], 0, 0, 0);
                    acc[1][1] = __builtin_amdgcn_mfma_f32_16x16x32_f16(W1, A1, acc[1][1], 0, 0, 0);
                    acc[2][0] = __builtin_amdgcn_mfma_f32_16x16x32_f16(W0, A2, acc[2][0], 0, 0, 0);
                    acc[2][1] = __builtin_amdgcn_mfma_f32_16x16x32_f16(W1, A2, acc[2][1], 0, 0, 0);
                    acc[3][0] = __builtin_amdgcn_mfma_f32_16x16x32_f16(W0, A3, acc[3][0], 0, 0, 0);
                    acc[3][1] = __builtin_amdgcn_mfma_f32_16x16x32_f16(W1, A3, acc[3][1], 0, 0, 0);
                }
            }
        }

        // epilogue row y: px = x0 + pg*64 + m*16 + lr, co = cg*32+n*16+lg*4+q
        const size_t rb = (img + y) * 256;
#pragma unroll
        for (int m = 0; m < 4; ++m) {
            f16* ap = act + (rb + x0 + pg * 64 + m * 16 + lr) * 64 + cg * 32 + lg * 4;
#pragma unroll
            for (int n = 0; n < 2; ++n) {
                f16x4 o;
#pragma unroll
                for (int q = 0; q < 4; ++q) {
                    float v = acc[m][n][q] + bias[n][q];
                    v = v / (1.f + __expf(-v));
                    o[q] = (f16)v;
                }
                *reinterpret_cast<f16x4*>(ap + n * 16) = o;
            }
        }
        __syncthreads();
    }
}

// K2: conv2 (64->1) + *dt -> psi. NHWC fp16 input, f16x8 vector loads.
__global__ __launch_bounds__(256) void k_conv2(
        const f16* __restrict__ act, const float* __restrict__ w2,
        const float* __restrict__ b2, const float* __restrict__ dtp,
        float* __restrict__ psi) {
    const int tx = threadIdx.x & 31, ty = threadIdx.x >> 5;
    const int px = blockIdx.x * 32 + tx;
    const int py = blockIdx.y * 8 + ty;
    const int b = blockIdx.z;

    float a0 = 0.f, a1 = 0.f, a2 = 0.f, a3 = 0.f;
#pragma unroll
    for (int dy = -1; dy <= 1; ++dy) {
        const int yy = py + dy;
        if ((unsigned)yy >= (unsigned)H) continue;
#pragma unroll
        for (int dx = -1; dx <= 1; ++dx) {
            const int xx = px + dx;
            const int k9 = (dy + 1) * 3 + (dx + 1);
            if ((unsigned)xx < (unsigned)W) {
                const f16x8* ap = reinterpret_cast<const f16x8*>(
                    act + (((size_t)b * H + yy) * W + xx) * 64);
                const float* wp = w2 + k9;
#pragma unroll
                for (int g = 0; g < 8; ++g) {
                    const f16x8 v = ap[g];
                    const int cb = g * 8;
                    a0 = fmaf((float)v[0], wp[(cb + 0) * 9], a0);
                    a1 = fmaf((float)v[1], wp[(cb + 1) * 9], a1);
                    a2 = fmaf((float)v[2], wp[(cb + 2) * 9], a2);
                    a3 = fmaf((float)v[3], wp[(cb + 3) * 9], a3);
                    a0 = fmaf((float)v[4], wp[(cb + 4) * 9], a0);
                    a1 = fmaf((float)v[5], wp[(cb + 5) * 9], a1);
                    a2 = fmaf((float)v[6], wp[(cb + 6) * 9], a2);
                    a3 = fmaf((float)v[7], wp[(cb + 7) * 9], a3);
                }
            }
        }
    }
    psi[((size_t)b * H + py) * W + px] = ((a0 + a1) + (a2 + a3) + b2[0]) * dtp[0];
}

// K3 v3: block = 1 row-half (128 px) x ALL 128 channels (proven R8/R11).
__global__ __launch_bounds__(256, 4) void k_sample3(
        const f16* __restrict__ Xt_r, const f16* __restrict__ Xt_i,
        const float* __restrict__ psi, float* __restrict__ out) {
    __shared__ int   s_off[4][128];
    __shared__ float s_w[4][128];
    __shared__ __align__(16) float s_stage[64][132];

    const int tid = threadIdx.x;
    const int bid = blockIdx.x;
    const int swz = (bid & 7) * 256 + (bid >> 3);
    const int seg = swz & 1, y = (swz >> 1) & 255, b = swz >> 9;
    const int x0 = seg * 128;

    if (tid < 128) {
        const int px = x0 + tid;
        const float* pb = psi + b * HWp;
        const int yp = min(y + 1, H - 1), ym = max(y - 1, 0);
        const int xp = min(px + 1, W - 1), xm = max(px - 1, 0);
        const float u = 0.5f * (pb[yp * W + px] - pb[ym * W + px]);
        const float v = -0.5f * (pb[y * W + xp] - pb[y * W + xm]);
        const float gx = (-1.f + 2.f * px / (float)(W - 1)) - u * (2.f / (float)W);
        const float gy = (-1.f + 2.f * y / (float)(H - 1)) - v * (2.f / (float)H);
        float ix = fminf(fmaxf((gx + 1.f) * 0.5f * (float)(W - 1), 0.f), (float)(W - 1));
        float iy = fminf(fmaxf((gy + 1.f) * 0.5f * (float)(H - 1), 0.f), (float)(H - 1));
        const float xf = floorf(ix), yf = floorf(iy);
        const float wx = ix - xf, wy = iy - yf;
        const int ix0 = (int)xf, iy0 = (int)yf;
        const int ix1 = min(ix0 + 1, W - 1), iy1 = min(iy0 + 1, H - 1);
        s_off[0][tid] = (iy0 * W + ix0) * 128;
        s_off[1][tid] = (iy0 * W + ix1) * 128;
        s_off[2][tid] = (iy1 * W + ix0) * 128;
        s_off[3][tid] = (iy1 * W + ix1) * 128;
        s_w[0][tid] = (1.f - wx) * (1.f - wy);
        s_w[1][tid] = wx * (1.f - wy);
        s_w[2][tid] = (1.f - wx) * wy;
        s_w[3][tid] = wx * wy;
    }
    __syncthreads();

    const int p = tid >> 1, s = tid & 1;
    const int o0 = s_off[0][p], o1 = s_off[1][p], o2 = s_off[2][p], o3 = s_off[3][p];
    const float w0 = s_w[0][p], w1 = s_w[1][p], w2 = s_w[2][p], w3 = s_w[3][p];
    const int cl = tid >> 5;
    const int pxq = (tid & 31) * 4;
    const size_t obase = (size_t)b * 128 * HWp + (size_t)y * W + x0 + pxq;

#pragma unroll
    for (int pl = 0; pl < 2; ++pl) {
        const char* base = (const char*)(pl ? Xt_i : Xt_r)
                         + (size_t)b * HWp * 128 + s * 64;
        const char* c0 = base + o0;
        const char* c1 = base + o1;
        const char* c2 = base + o2;
        const char* c3 = base + o3;
        f16x8 h00 = *(const f16x8*)(c0);      f16x8 h01 = *(const f16x8*)(c0 + 16);
        f16x8 h02 = *(const f16x8*)(c0 + 32); f16x8 h03 = *(const f16x8*)(c0 + 48);
        f16x8 h10 = *(const f16x8*)(c1);      f16x8 h11 = *(const f16x8*)(c1 + 16);
        f16x8 h12 = *(const f16x8*)(c1 + 32); f16x8 h13 = *(const f16x8*)(c1 + 48);
        f16x8 h20 = *(const f16x8*)(c2);      f16x8 h21 = *(const f16x8*)(c2 + 16);
        f16x8 h22 = *(const f16x8*)(c2 + 32); f16x8 h23 = *(const f16x8*)(c2 + 48);
        f16x8 h30 = *(const f16x8*)(c3);      f16x8 h31 = *(const f16x8*)(c3 + 16);
        f16x8 h32 = *(const f16x8*)(c3 + 32); f16x8 h33 = *(const f16x8*)(c3 + 48);

        const int rb = s << 5;
#pragma unroll
        for (int k = 0; k < 8; ++k) {
            s_stage[rb + k][p] = w0 * (float)h00[k] + w1 * (float)h10[k]
                               + w2 * (float)h20[k] + w3 * (float)h30[k];
            s_stage[rb + 8 + k][p] = w0 * (float)h01[k] + w1 * (float)h11[k]
                                   + w2 * (float)h21[k] + w3 * (float)h31[k];
            s_stage[rb + 16 + k][p] = w0 * (float)h02[k] + w1 * (float)h12[k]
                                    + w2 * (float)h22[k] + w3 * (float)h32[k];
            s_stage[rb + 24 + k][p] = w0 * (float)h03[k] + w1 * (float)h13[k]
                                    + w2 * (float)h23[k] + w3 * (float)h33[k];
        }
        __syncthreads();
#pragma unroll
        for (int k = 0; k < 8; ++k) {
            const int c = cl + (k << 3);
            f32x4 vv = *(const f32x4*)&s_stage[c][pxq];
            *(f32x4*)(out + obase + (size_t)(pl * 64 + c) * HWp) = vv;
        }
        __syncthreads();
    }
}

// K3 fallback: scalar gather from fp32 NCHW.
__global__ __launch_bounds__(256) void k_sample_fb(
        const float* __restrict__ zr, const float* __restrict__ zi,
        const float* __restrict__ psi, float* __restrict__ out) {
    const int tx = threadIdx.x & 31, ty = threadIdx.x >> 5;
    const int px = blockIdx.x * 32 + tx;
    const int py = blockIdx.y * 8 + ty;
    const int b  = blockIdx.z >> 3;
    const int c0 = (blockIdx.z & 7) * 16;

    const float* pb = psi + b * HWp;
    const int yp = min(py + 1, H - 1), ym = max(py - 1, 0);
    const int xp = min(px + 1, W - 1), xm = max(px - 1, 0);
    const float u = 0.5f * (pb[yp * W + px] - pb[ym * W + px]);
    const float v = -0.5f * (pb[py * W + xp] - pb[py * W + xm]);

    const float gx = (-1.f + 2.f * px / (float)(W - 1)) - u * (2.f / (float)W);
    const float gy = (-1.f + 2.f * py / (float)(H - 1)) - v * (2.f / (float)H);

    float ix = fminf(fmaxf((gx + 1.f) * 0.5f * (float)(W - 1), 0.f), (float)(W - 1));
    float iy = fminf(fmaxf((gy + 1.f) * 0.5f * (float)(H - 1), 0.f), (float)(H - 1));
    const float xf = floorf(ix), yf = floorf(iy);
    const float wx = ix - xf, wy = iy - yf;
    const int ix0 = (int)xf, iy0 = (int)yf;
    const int ix1 = min(ix0 + 1, W - 1), iy1 = min(iy0 + 1, H - 1);

    const int o00 = iy0 * W + ix0, o01 = iy0 * W + ix1;
    const int o10 = iy1 * W + ix0, o11 = iy1 * W + ix1;
    const float w00 = (1.f - wx) * (1.f - wy), w01 = wx * (1.f - wy);
    const float w10 = (1.f - wx) * wy, w11 = wx * wy;

    const float* src0 = (c0 < 64) ? (zr + (size_t)b * 64 * HWp + (size_t)c0 * HWp)
                                  : (zi + (size_t)b * 64 * HWp + (size_t)(c0 - 64) * HWp);
    float* ob = out + ((size_t)b * 128 + c0) * HWp + py * W + px;
#pragma unroll
    for (int c = 0; c < 16; ++c) {
        const float* p = src0 + (size_t)c * HWp;
        ob[(size_t)c * HWp] = p[o00] * w00 + p[o01] * w01 + p[o10] * w10 + p[o11] * w11;
    }
}

extern "C" void kernel_launch(void* const* d_in, const int* in_sizes, int n_in,
                              void* d_out, int out_size, void* d_ws, size_t ws_size,
                              hipStream_t stream) {
    const float* z_real = (const float*)d_in[0];
    const float* z_imag = (const float*)d_in[1];
    const float* dt     = (const float*)d_in[2];
    const float* w1     = (const float*)d_in[3];
    const float* b1     = (const float*)d_in[4];
    const float* w2     = (const float*)d_in[5];
    const float* b2     = (const float*)d_in[6];

    float* out = (float*)d_out;
    char* ws = (char*)d_ws;
    f16* w1tb = (f16*)ws;                       // 73728 B

    if (ws_size >= NEED_FAST) {
        // ws layout: w1tb | Xt_r | Xt_i | psi
        f16* Xt_r  = (f16*)(ws + 73728);
        f16* Xt_i  = (f16*)(ws + 73728 + PLANE);
        float* psi = (float*)(ws + 73728 + 2 * PLANE);
        f16* act   = (f16*)d_out;   // consumed by conv2 before sample3 overwrites

        hipLaunchKernelGGL(k_xt2, dim3(HWp / 64, 9), dim3(256), 0, stream,
                           z_real, z_imag, Xt_r, Xt_i, w1, w1tb, 8);
        hipLaunchKernelGGL(k_conv1, dim3(512), dim3(256), 0, stream, Xt_r, w1tb, b1, act);
        hipLaunchKernelGGL(k_conv2, dim3(8, 32, 4), dim3(256), 0, stream, act, w2, b2, dt, psi);
        hipLaunchKernelGGL(k_sample3, dim3(2048), dim3(256), 0, stream,
                           Xt_r, Xt_i, psi, out);
    } else {
        float* psi = (float*)(ws + 73728);
        f16* Xt  = (f16*)((char*)d_out + 4096);
        f16* act = (f16*)((char*)d_out + 4096 + PLANE);

        hipLaunchKernelGGL(k_xt2, dim3(HWp / 64, 5), dim3(256), 0, stream,
                           z_real, z_real, Xt, Xt, w1, w1tb, 4);
        hipLaunchKernelGGL(k_conv1, dim3(512), dim3(256), 0, stream, Xt, w1tb, b1, act);
        hipLaunchKernelGGL(k_conv2, dim3(8, 32, 4), dim3(256), 0, stream, act, w2, b2, dt, psi);
        hipLaunchKernelGGL(k_sample_fb, dim3(8, 32, 32), dim3(256), 0, stream,
                           z_real, z_imag, psi, out);
    }
}

// Round 16
// 156.354 us; speedup vs baseline: 1.4049x; 1.0377x over previous
//
#include <hip/hip_runtime.h>
#include <cmath>

namespace {
constexpr int H = 256, W = 256, HWp = H * W;
constexpr size_t PLANE = (size_t)4 * HWp * 64 * 2;  // one NHWC fp16 tensor, bytes
constexpr size_t NEED_FAST = 73728 + 2 * PLANE + (1u << 20);
}

typedef _Float16 f16;
typedef unsigned int u32;
typedef __attribute__((ext_vector_type(4))) _Float16 f16x4;
typedef __attribute__((ext_vector_type(8))) _Float16 f16x8;
typedef __attribute__((ext_vector_type(4))) float f32x4;
typedef __attribute__((ext_vector_type(4))) unsigned int u32x4;

__device__ __forceinline__ void dma16(const char* g, char* l) {
    __builtin_amdgcn_global_load_lds(
        (const __attribute__((address_space(1))) u32*)g,
        (__attribute__((address_space(3))) u32*)l, 16, 0, 0);
}

// K_xt2: NCHW fp32 -> NHWC fp16 for both tensors; last y-slice does the
// weight transform w1 [co][ci][3][3] fp32 -> w1tb [k9][co][ci] fp16.
__global__ __launch_bounds__(256) void k_xt2(const float* __restrict__ zr,
                                             const float* __restrict__ zi,
                                             f16* __restrict__ Xt_r,
                                             f16* __restrict__ Xt_i,
                                             const float* __restrict__ w1,
                                             f16* __restrict__ w1tb,
                                             int ny_xt) {
    if ((int)blockIdx.y == ny_xt) {
        int i = blockIdx.x * 256 + threadIdx.x;
        if (i < 64 * 576) {
            int co = i / 576, r = i - co * 576;
            int ci = r / 9, k9 = r - ci * 9;
            w1tb[(k9 * 64 + co) * 64 + ci] = (f16)w1[i];
        }
        return;
    }
    __shared__ f16 tile[64][80];
    const int t = threadIdx.x;
    const int p0 = blockIdx.x * 64;
    const int bb = blockIdx.y & 3;
    const bool im = blockIdx.y >= 4;
    const float* x = im ? zi : zr;
    f16* dst = im ? Xt_i : Xt_r;
    const size_t base = (size_t)bb * 64 * HWp;
#pragma unroll
    for (int r = 0; r < 4; ++r) {
        int q = r * 256 + t;
        int ci = q >> 4, px4 = (q & 15) * 4;
        f32x4 v = *reinterpret_cast<const f32x4*>(x + base + (size_t)ci * HWp + p0 + px4);
#pragma unroll
        for (int j = 0; j < 4; ++j) tile[px4 + j][ci] = (f16)v[j];
    }
    __syncthreads();
    const int px = t >> 2, q = t & 3;
    u32x4* d = reinterpret_cast<u32x4*>(dst + ((size_t)bb * HWp + p0 + px) * 64 + q * 16);
    const u32x4* s = reinterpret_cast<const u32x4*>(&tile[px][q * 16]);
    d[0] = s[0];
    d[1] = s[1];
}

// K1 v9: conv1 row-marching ring (R11 v6 structure) + counted-vmcnt raw
// barriers (T3/T4 style): prefetch DMA and epilogue stores stay in flight
// across the per-row barrier instead of a full vmcnt(0) drain.
__global__ __launch_bounds__(512, 1) void k_conv1(
        const f16* __restrict__ Xt, const f16* __restrict__ w1tb,
        const float* __restrict__ b1, f16* __restrict__ act) {
    __shared__ __align__(16) char lds[131072];   // 4 ring slots x 32 KB

    const int tid = threadIdx.x;
    const int lane = tid & 63, wid = tid >> 6;
    const int lr = lane & 15, lg = lane >> 4;
    const int pg = wid & 3, cg = wid >> 2;       // 64-px group, 32-co group

    const int bid = blockIdx.x;                  // 0..255
    const int swz = (bid & 7) * 32 + (bid >> 3); // XCD-contiguous row-quads
    const int b = swz >> 6;
    const int y0 = (swz & 63) * 4;

    const int swzb = (lane ^ ((lane >> 3) & 7)) << 4;
    const size_t img = (size_t)b * 256;

    f16x8 Wreg[9][2][2];
#pragma unroll
    for (int k9 = 0; k9 < 9; ++k9)
#pragma unroll
        for (int n = 0; n < 2; ++n)
#pragma unroll
            for (int c = 0; c < 2; ++c)
                Wreg[k9][n][c] = *reinterpret_cast<const f16x8*>(
                    w1tb + (size_t)(k9 * 64 + cg * 32 + n * 16 + lr) * 64
                         + c * 32 + lg * 8);

    float bias[2][4];
#pragma unroll
    for (int n = 0; n < 2; ++n) {
        f32x4 bv = *reinterpret_cast<const f32x4*>(b1 + cg * 32 + n * 16 + lg * 4);
#pragma unroll
        for (int r = 0; r < 4; ++r) bias[n][r] = bv[r];
    }

    // stage one full input row (32 KB) into ring slot yy&3; exactly 4 dma16
    // per wave (vmcnt accounting relies on this).
    auto stage = [&](int yy) {
        const char* src = (const char*)Xt + ((img + yy) * 256) * 128 + swzb;
        char* dst = lds + (yy & 3) * 32768;
#pragma unroll
        for (int i = 0; i < 4; ++i) {
            const int ch = wid + i * 8;          // 32 chunks of 1 KB
            dma16(src + ch * 1024, dst + ch * 1024);
        }
    };

    if (y0 > 0) stage(y0 - 1);
    stage(y0);
    stage(y0 + 1);
    asm volatile("s_waitcnt vmcnt(0)" ::: "memory");
    asm volatile("s_barrier" ::: "memory");
    __builtin_amdgcn_sched_barrier(0);

    const f16x8 zf = (f16x8)(f16)0.f;

    for (int r = 0; r < 4; ++r) {
        const int y = y0 + r;
        const int yn = y + 2;
        const bool do_stage = (r < 3 && yn < 256);
        if (do_stage) stage(yn);                 // slot (y+2)&3: disjoint

        if (r > 0) {
            // need stage(y+1) (issued last iter) landed; allow last iter's
            // 8 epilogue stores (+ this iter's 4 loads, if issued) in flight.
            if (do_stage) asm volatile("s_waitcnt vmcnt(12)" ::: "memory");
            else          asm volatile("s_waitcnt vmcnt(8)"  ::: "memory");
            asm volatile("s_barrier" ::: "memory");
            __builtin_amdgcn_sched_barrier(0);
        }

        f32x4 acc[4][2];
#pragma unroll
        for (int m = 0; m < 4; ++m)
#pragma unroll
            for (int n = 0; n < 2; ++n) acc[m][n] = (f32x4)0.f;

#pragma unroll
        for (int dyi = 0; dyi < 3; ++dyi) {
            const int yy = y + dyi - 1;
            if ((unsigned)yy >= 256u) continue;  // image-edge zero pad (uniform)
            const char* sb = lds + (yy & 3) * 32768;
#pragma unroll
            for (int kx = 0; kx < 3; ++kx) {
                const int dx = kx - 1;
                const int px1 = pg * 64 + 16 + lr + dx;          // m=1 (always in)
                const bool ok0 = (unsigned)(px1 - 16) < 256u;    // m=0 edge
                const bool ok3 = (unsigned)(px1 + 32) < 256u;    // m=3 edge
                const int px0 = ok0 ? px1 - 16 : px1 - 16 - dx;  // clamped addr
                const int px2 = px1 + 16;
                const int px3 = ok3 ? px1 + 32 : px1 + 32 - dx;
                const int k9 = dyi * 3 + kx;
#pragma unroll
                for (int c = 0; c < 2; ++c) {
                    const int pe = c * 4 + lg;
                    f16x8 A0 = *(const f16x8*)(sb + (px0 << 7) + ((pe ^ (px0 & 7)) << 4));
                    f16x8 A1 = *(const f16x8*)(sb + (px1 << 7) + ((pe ^ (px1 & 7)) << 4));
                    f16x8 A2 = *(const f16x8*)(sb + (px2 << 7) + ((pe ^ (px2 & 7)) << 4));
                    f16x8 A3 = *(const f16x8*)(sb + (px3 << 7) + ((pe ^ (px3 & 7)) << 4));
                    A0 = ok0 ? A0 : zf;
                    A3 = ok3 ? A3 : zf;
                    const f16x8 W0 = Wreg[k9][0][c];
                    const f16x8 W1 = Wreg[k9][1][c];
                    acc[0][0] = __builtin_amdgcn_mfma_f32_16x16x32_f16(W0, A0, acc[0][0], 0, 0, 0);
                    acc[0][1] = __builtin_amdgcn_mfma_f32_16x16x32_f16(W1, A0, acc[0][1], 0, 0, 0);
                    acc[1][0] = __builtin_amdgcn_mfma_f32_16x16x32_f16(W0, A1, acc[1][0], 0, 0, 0);
                    acc[1][1] = __builtin_amdgcn_mfma_f32_16x16x32_f16(W1, A1, acc[1][1], 0, 0, 0);
                    acc[2][0] = __builtin_amdgcn_mfma_f32_16x16x32_f16(W0, A2, acc[2][0], 0, 0, 0);
                    acc[2][1] = __builtin_amdgcn_mfma_f32_16x16x32_f16(W1, A2, acc[2][1], 0, 0, 0);
                    acc[3][0] = __builtin_amdgcn_mfma_f32_16x16x32_f16(W0, A3, acc[3][0], 0, 0, 0);
                    acc[3][1] = __builtin_amdgcn_mfma_f32_16x16x32_f16(W1, A3, acc[3][1], 0, 0, 0);
                }
            }
        }

        // epilogue row y: exactly 8 stores per wave (vmcnt accounting).
        const size_t rb = (img + y) * 256;
#pragma unroll
        for (int m = 0; m < 4; ++m) {
            f16* ap = act + (rb + pg * 64 + m * 16 + lr) * 64 + cg * 32 + lg * 4;
#pragma unroll
            for (int n = 0; n < 2; ++n) {
                f16x4 o;
#pragma unroll
                for (int q = 0; q < 4; ++q) {
                    float v = acc[m][n][q] + bias[n][q];
                    v = v / (1.f + __expf(-v));
                    o[q] = (f16)v;
                }
                *reinterpret_cast<f16x4*>(ap + n * 16) = o;
            }
        }
        if (r < 3) {                             // slot-reuse safety, no drain
            asm volatile("s_barrier" ::: "memory");
            __builtin_amdgcn_sched_barrier(0);
        }
    }
}

// K2: conv2 (64->1) + *dt -> psi. NHWC fp16 input, f16x8 vector loads.
__global__ __launch_bounds__(256) void k_conv2(
        const f16* __restrict__ act, const float* __restrict__ w2,
        const float* __restrict__ b2, const float* __restrict__ dtp,
        float* __restrict__ psi) {
    const int tx = threadIdx.x & 31, ty = threadIdx.x >> 5;
    const int px = blockIdx.x * 32 + tx;
    const int py = blockIdx.y * 8 + ty;
    const int b = blockIdx.z;

    float a0 = 0.f, a1 = 0.f, a2 = 0.f, a3 = 0.f;
#pragma unroll
    for (int dy = -1; dy <= 1; ++dy) {
        const int yy = py + dy;
        if ((unsigned)yy >= (unsigned)H) continue;
#pragma unroll
        for (int dx = -1; dx <= 1; ++dx) {
            const int xx = px + dx;
            const int k9 = (dy + 1) * 3 + (dx + 1);
            if ((unsigned)xx < (unsigned)W) {
                const f16x8* ap = reinterpret_cast<const f16x8*>(
                    act + (((size_t)b * H + yy) * W + xx) * 64);
                const float* wp = w2 + k9;
#pragma unroll
                for (int g = 0; g < 8; ++g) {
                    const f16x8 v = ap[g];
                    const int cb = g * 8;
                    a0 = fmaf((float)v[0], wp[(cb + 0) * 9], a0);
                    a1 = fmaf((float)v[1], wp[(cb + 1) * 9], a1);
                    a2 = fmaf((float)v[2], wp[(cb + 2) * 9], a2);
                    a3 = fmaf((float)v[3], wp[(cb + 3) * 9], a3);
                    a0 = fmaf((float)v[4], wp[(cb + 4) * 9], a0);
                    a1 = fmaf((float)v[5], wp[(cb + 5) * 9], a1);
                    a2 = fmaf((float)v[6], wp[(cb + 6) * 9], a2);
                    a3 = fmaf((float)v[7], wp[(cb + 7) * 9], a3);
                }
            }
        }
    }
    psi[((size_t)b * H + py) * W + px] = ((a0 + a1) + (a2 + a3) + b2[0]) * dtp[0];
}

// K3 v3: block = 1 row-half (128 px) x ALL 128 channels (proven R8/R11).
__global__ __launch_bounds__(256, 4) void k_sample3(
        const f16* __restrict__ Xt_r, const f16* __restrict__ Xt_i,
        const float* __restrict__ psi, float* __restrict__ out) {
    __shared__ int   s_off[4][128];
    __shared__ float s_w[4][128];
    __shared__ __align__(16) float s_stage[64][132];

    const int tid = threadIdx.x;
    const int bid = blockIdx.x;
    const int swz = (bid & 7) * 256 + (bid >> 3);
    const int seg = swz & 1, y = (swz >> 1) & 255, b = swz >> 9;
    const int x0 = seg * 128;

    if (tid < 128) {
        const int px = x0 + tid;
        const float* pb = psi + b * HWp;
        const int yp = min(y + 1, H - 1), ym = max(y - 1, 0);
        const int xp = min(px + 1, W - 1), xm = max(px - 1, 0);
        const float u = 0.5f * (pb[yp * W + px] - pb[ym * W + px]);
        const float v = -0.5f * (pb[y * W + xp] - pb[y * W + xm]);
        const float gx = (-1.f + 2.f * px / (float)(W - 1)) - u * (2.f / (float)W);
        const float gy = (-1.f + 2.f * y / (float)(H - 1)) - v * (2.f / (float)H);
        float ix = fminf(fmaxf((gx + 1.f) * 0.5f * (float)(W - 1), 0.f), (float)(W - 1));
        float iy = fminf(fmaxf((gy + 1.f) * 0.5f * (float)(H - 1), 0.f), (float)(H - 1));
        const float xf = floorf(ix), yf = floorf(iy);
        const float wx = ix - xf, wy = iy - yf;
        const int ix0 = (int)xf, iy0 = (int)yf;
        const int ix1 = min(ix0 + 1, W - 1), iy1 = min(iy0 + 1, H - 1);
        s_off[0][tid] = (iy0 * W + ix0) * 128;
        s_off[1][tid] = (iy0 * W + ix1) * 128;
        s_off[2][tid] = (iy1 * W + ix0) * 128;
        s_off[3][tid] = (iy1 * W + ix1) * 128;
        s_w[0][tid] = (1.f - wx) * (1.f - wy);
        s_w[1][tid] = wx * (1.f - wy);
        s_w[2][tid] = (1.f - wx) * wy;
        s_w[3][tid] = wx * wy;
    }
    __syncthreads();

    const int p = tid >> 1, s = tid & 1;
    const int o0 = s_off[0][p], o1 = s_off[1][p], o2 = s_off[2][p], o3 = s_off[3][p];
    const float w0 = s_w[0][p], w1 = s_w[1][p], w2 = s_w[2][p], w3 = s_w[3][p];
    const int cl = tid >> 5;
    const int pxq = (tid & 31) * 4;
    const size_t obase = (size_t)b * 128 * HWp + (size_t)y * W + x0 + pxq;

#pragma unroll
    for (int pl = 0; pl < 2; ++pl) {
        const char* base = (const char*)(pl ? Xt_i : Xt_r)
                         + (size_t)b * HWp * 128 + s * 64;
        const char* c0 = base + o0;
        const char* c1 = base + o1;
        const char* c2 = base + o2;
        const char* c3 = base + o3;
        f16x8 h00 = *(const f16x8*)(c0);      f16x8 h01 = *(const f16x8*)(c0 + 16);
        f16x8 h02 = *(const f16x8*)(c0 + 32); f16x8 h03 = *(const f16x8*)(c0 + 48);
        f16x8 h10 = *(const f16x8*)(c1);      f16x8 h11 = *(const f16x8*)(c1 + 16);
        f16x8 h12 = *(const f16x8*)(c1 + 32); f16x8 h13 = *(const f16x8*)(c1 + 48);
        f16x8 h20 = *(const f16x8*)(c2);      f16x8 h21 = *(const f16x8*)(c2 + 16);
        f16x8 h22 = *(const f16x8*)(c2 + 32); f16x8 h23 = *(const f16x8*)(c2 + 48);
        f16x8 h30 = *(const f16x8*)(c3);      f16x8 h31 = *(const f16x8*)(c3 + 16);
        f16x8 h32 = *(const f16x8*)(c3 + 32); f16x8 h33 = *(const f16x8*)(c3 + 48);

        const int rb = s << 5;
#pragma unroll
        for (int k = 0; k < 8; ++k) {
            s_stage[rb + k][p] = w0 * (float)h00[k] + w1 * (float)h10[k]
                               + w2 * (float)h20[k] + w3 * (float)h30[k];
            s_stage[rb + 8 + k][p] = w0 * (float)h01[k] + w1 * (float)h11[k]
                                   + w2 * (float)h21[k] + w3 * (float)h31[k];
            s_stage[rb + 16 + k][p] = w0 * (float)h02[k] + w1 * (float)h12[k]
                                    + w2 * (float)h22[k] + w3 * (float)h32[k];
            s_stage[rb + 24 + k][p] = w0 * (float)h03[k] + w1 * (float)h13[k]
                                    + w2 * (float)h23[k] + w3 * (float)h33[k];
        }
        __syncthreads();
#pragma unroll
        for (int k = 0; k < 8; ++k) {
            const int c = cl + (k << 3);
            f32x4 vv = *(const f32x4*)&s_stage[c][pxq];
            *(f32x4*)(out + obase + (size_t)(pl * 64 + c) * HWp) = vv;
        }
        __syncthreads();
    }
}

// K3 fallback: scalar gather from fp32 NCHW.
__global__ __launch_bounds__(256) void k_sample_fb(
        const float* __restrict__ zr, const float* __restrict__ zi,
        const float* __restrict__ psi, float* __restrict__ out) {
    const int tx = threadIdx.x & 31, ty = threadIdx.x >> 5;
    const int px = blockIdx.x * 32 + tx;
    const int py = blockIdx.y * 8 + ty;
    const int b  = blockIdx.z >> 3;
    const int c0 = (blockIdx.z & 7) * 16;

    const float* pb = psi + b * HWp;
    const int yp = min(py + 1, H - 1), ym = max(py - 1, 0);
    const int xp = min(px + 1, W - 1), xm = max(px - 1, 0);
    const float u = 0.5f * (pb[yp * W + px] - pb[ym * W + px]);
    const float v = -0.5f * (pb[py * W + xp] - pb[py * W + xm]);

    const float gx = (-1.f + 2.f * px / (float)(W - 1)) - u * (2.f / (float)W);
    const float gy = (-1.f + 2.f * py / (float)(H - 1)) - v * (2.f / (float)H);

    float ix = fminf(fmaxf((gx + 1.f) * 0.5f * (float)(W - 1), 0.f), (float)(W - 1));
    float iy = fminf(fmaxf((gy + 1.f) * 0.5f * (float)(H - 1), 0.f), (float)(H - 1));
    const float xf = floorf(ix), yf = floorf(iy);
    const float wx = ix - xf, wy = iy - yf;
    const int ix0 = (int)xf, iy0 = (int)yf;
    const int ix1 = min(ix0 + 1, W - 1), iy1 = min(iy0 + 1, H - 1);

    const int o00 = iy0 * W + ix0, o01 = iy0 * W + ix1;
    const int o10 = iy1 * W + ix0, o11 = iy1 * W + ix1;
    const float w00 = (1.f - wx) * (1.f - wy), w01 = wx * (1.f - wy);
    const float w10 = (1.f - wx) * wy, w11 = wx * wy;

    const float* src0 = (c0 < 64) ? (zr + (size_t)b * 64 * HWp + (size_t)c0 * HWp)
                                  : (zi + (size_t)b * 64 * HWp + (size_t)(c0 - 64) * HWp);
    float* ob = out + ((size_t)b * 128 + c0) * HWp + py * W + px;
#pragma unroll
    for (int c = 0; c < 16; ++c) {
        const float* p = src0 + (size_t)c * HWp;
        ob[(size_t)c * HWp] = p[o00] * w00 + p[o01] * w01 + p[o10] * w10 + p[o11] * w11;
    }
}

extern "C" void kernel_launch(void* const* d_in, const int* in_sizes, int n_in,
                              void* d_out, int out_size, void* d_ws, size_t ws_size,
                              hipStream_t stream) {
    const float* z_real = (const float*)d_in[0];
    const float* z_imag = (const float*)d_in[1];
    const float* dt     = (const float*)d_in[2];
    const float* w1     = (const float*)d_in[3];
    const float* b1     = (const float*)d_in[4];
    const float* w2     = (const float*)d_in[5];
    const float* b2     = (const float*)d_in[6];

    float* out = (float*)d_out;
    char* ws = (char*)d_ws;
    f16* w1tb = (f16*)ws;                       // 73728 B

    if (ws_size >= NEED_FAST) {
        // ws layout: w1tb | Xt_r | Xt_i | psi
        f16* Xt_r  = (f16*)(ws + 73728);
        f16* Xt_i  = (f16*)(ws + 73728 + PLANE);
        float* psi = (float*)(ws + 73728 + 2 * PLANE);
        f16* act   = (f16*)d_out;   // consumed by conv2 before sample3 overwrites

        hipLaunchKernelGGL(k_xt2, dim3(HWp / 64, 9), dim3(256), 0, stream,
                           z_real, z_imag, Xt_r, Xt_i, w1, w1tb, 8);
        hipLaunchKernelGGL(k_conv1, dim3(256), dim3(512), 0, stream, Xt_r, w1tb, b1, act);
        hipLaunchKernelGGL(k_conv2, dim3(8, 32, 4), dim3(256), 0, stream, act, w2, b2, dt, psi);
        hipLaunchKernelGGL(k_sample3, dim3(2048), dim3(256), 0, stream,
                           Xt_r, Xt_i, psi, out);
    } else {
        float* psi = (float*)(ws + 73728);
        f16* Xt  = (f16*)((char*)d_out + 4096);
        f16* act = (f16*)((char*)d_out + 4096 + PLANE);

        hipLaunchKernelGGL(k_xt2, dim3(HWp / 64, 5), dim3(256), 0, stream,
                           z_real, z_real, Xt, Xt, w1, w1tb, 4);
        hipLaunchKernelGGL(k_conv1, dim3(256), dim3(512), 0, stream, Xt, w1tb, b1, act);
        hipLaunchKernelGGL(k_conv2, dim3(8, 32, 4), dim3(256), 0, stream, act, w2, b2, dt, psi);
        hipLaunchKernelGGL(k_sample_fb, dim3(8, 32, 32), dim3(256), 0, stream,
                           z_real, z_imag, psi, out);
    }
}

// Round 17
// 151.292 us; speedup vs baseline: 1.4519x; 1.0335x over previous
//
#include <hip/hip_runtime.h>
#include <cmath>

namespace {
constexpr int H = 256, W = 256, HWp = H * W;
constexpr size_t PLANE = (size_t)4 * HWp * 64 * 2;  // one NHWC fp16 tensor, bytes
constexpr size_t WOFF2 = 73728;                      // w2t offset (f16, 576 el)
constexpr size_t WS0  = 75776;                       // end of weight area
constexpr size_t NEED_FAST = WS0 + 2 * PLANE + (1u << 20);
}

typedef _Float16 f16;
typedef unsigned int u32;
typedef __attribute__((ext_vector_type(2))) _Float16 f16x2;
typedef __attribute__((ext_vector_type(4))) _Float16 f16x4;
typedef __attribute__((ext_vector_type(8))) _Float16 f16x8;
typedef __attribute__((ext_vector_type(4))) float f32x4;
typedef __attribute__((ext_vector_type(4))) unsigned int u32x4;

__device__ __forceinline__ void dma16(const char* g, char* l) {
    __builtin_amdgcn_global_load_lds(
        (const __attribute__((address_space(1))) u32*)g,
        (__attribute__((address_space(3))) u32*)l, 16, 0, 0);
}

// K_xt2: NCHW fp32 -> NHWC fp16 for both tensors; last y-slice does the
// weight transforms (w1 -> w1tb [k9][co][ci] f16; w2 -> w2t [k9][ci] f16).
__global__ __launch_bounds__(256) void k_xt2(const float* __restrict__ zr,
                                             const float* __restrict__ zi,
                                             f16* __restrict__ Xt_r,
                                             f16* __restrict__ Xt_i,
                                             const float* __restrict__ w1,
                                             f16* __restrict__ w1tb,
                                             const float* __restrict__ w2,
                                             f16* __restrict__ w2t,
                                             int ny_xt) {
    if ((int)blockIdx.y == ny_xt) {
        int i = blockIdx.x * 256 + threadIdx.x;
        if (i < 64 * 576) {
            int co = i / 576, r = i - co * 576;
            int ci = r / 9, k9 = r - ci * 9;
            w1tb[(k9 * 64 + co) * 64 + ci] = (f16)w1[i];
        }
        if (i < 576) {                           // w2 [ci][k9] -> w2t [k9][ci]
            int ci = i / 9, k9 = i - ci * 9;
            w2t[k9 * 64 + ci] = (f16)w2[i];
        }
        return;
    }
    __shared__ f16 tile[64][80];
    const int t = threadIdx.x;
    const int p0 = blockIdx.x * 64;
    const int bb = blockIdx.y & 3;
    const bool im = blockIdx.y >= 4;
    const float* x = im ? zi : zr;
    f16* dst = im ? Xt_i : Xt_r;
    const size_t base = (size_t)bb * 64 * HWp;
#pragma unroll
    for (int r = 0; r < 4; ++r) {
        int q = r * 256 + t;
        int ci = q >> 4, px4 = (q & 15) * 4;
        f32x4 v = *reinterpret_cast<const f32x4*>(x + base + (size_t)ci * HWp + p0 + px4);
#pragma unroll
        for (int j = 0; j < 4; ++j) tile[px4 + j][ci] = (f16)v[j];
    }
    __syncthreads();
    const int px = t >> 2, q = t & 3;
    u32x4* d = reinterpret_cast<u32x4*>(dst + ((size_t)bb * HWp + p0 + px) * 64 + q * 16);
    const u32x4* s = reinterpret_cast<const u32x4*>(&tile[px][q * 16]);
    d[0] = s[0];
    d[1] = s[1];
}

// K1 v9: conv1 row-marching ring + counted-vmcnt raw barriers (proven R16).
__global__ __launch_bounds__(512, 1) void k_conv1(
        const f16* __restrict__ Xt, const f16* __restrict__ w1tb,
        const float* __restrict__ b1, f16* __restrict__ act) {
    __shared__ __align__(16) char lds[131072];   // 4 ring slots x 32 KB

    const int tid = threadIdx.x;
    const int lane = tid & 63, wid = tid >> 6;
    const int lr = lane & 15, lg = lane >> 4;
    const int pg = wid & 3, cg = wid >> 2;

    const int bid = blockIdx.x;                  // 0..255
    const int swz = (bid & 7) * 32 + (bid >> 3);
    const int b = swz >> 6;
    const int y0 = (swz & 63) * 4;

    const int swzb = (lane ^ ((lane >> 3) & 7)) << 4;
    const size_t img = (size_t)b * 256;

    f16x8 Wreg[9][2][2];
#pragma unroll
    for (int k9 = 0; k9 < 9; ++k9)
#pragma unroll
        for (int n = 0; n < 2; ++n)
#pragma unroll
            for (int c = 0; c < 2; ++c)
                Wreg[k9][n][c] = *reinterpret_cast<const f16x8*>(
                    w1tb + (size_t)(k9 * 64 + cg * 32 + n * 16 + lr) * 64
                         + c * 32 + lg * 8);

    float bias[2][4];
#pragma unroll
    for (int n = 0; n < 2; ++n) {
        f32x4 bv = *reinterpret_cast<const f32x4*>(b1 + cg * 32 + n * 16 + lg * 4);
#pragma unroll
        for (int r = 0; r < 4; ++r) bias[n][r] = bv[r];
    }

    auto stage = [&](int yy) {                   // exactly 4 dma16 per wave
        const char* src = (const char*)Xt + ((img + yy) * 256) * 128 + swzb;
        char* dst = lds + (yy & 3) * 32768;
#pragma unroll
        for (int i = 0; i < 4; ++i) {
            const int ch = wid + i * 8;
            dma16(src + ch * 1024, dst + ch * 1024);
        }
    };

    if (y0 > 0) stage(y0 - 1);
    stage(y0);
    stage(y0 + 1);
    asm volatile("s_waitcnt vmcnt(0)" ::: "memory");
    asm volatile("s_barrier" ::: "memory");
    __builtin_amdgcn_sched_barrier(0);

    const f16x8 zf = (f16x8)(f16)0.f;

    for (int r = 0; r < 4; ++r) {
        const int y = y0 + r;
        const int yn = y + 2;
        const bool do_stage = (r < 3 && yn < 256);
        if (do_stage) stage(yn);

        if (r > 0) {
            if (do_stage) asm volatile("s_waitcnt vmcnt(12)" ::: "memory");
            else          asm volatile("s_waitcnt vmcnt(8)"  ::: "memory");
            asm volatile("s_barrier" ::: "memory");
            __builtin_amdgcn_sched_barrier(0);
        }

        f32x4 acc[4][2];
#pragma unroll
        for (int m = 0; m < 4; ++m)
#pragma unroll
            for (int n = 0; n < 2; ++n) acc[m][n] = (f32x4)0.f;

#pragma unroll
        for (int dyi = 0; dyi < 3; ++dyi) {
            const int yy = y + dyi - 1;
            if ((unsigned)yy >= 256u) continue;
            const char* sb = lds + (yy & 3) * 32768;
#pragma unroll
            for (int kx = 0; kx < 3; ++kx) {
                const int dx = kx - 1;
                const int px1 = pg * 64 + 16 + lr + dx;
                const bool ok0 = (unsigned)(px1 - 16) < 256u;
                const bool ok3 = (unsigned)(px1 + 32) < 256u;
                const int px0 = ok0 ? px1 - 16 : px1 - 16 - dx;
                const int px2 = px1 + 16;
                const int px3 = ok3 ? px1 + 32 : px1 + 32 - dx;
                const int k9 = dyi * 3 + kx;
#pragma unroll
                for (int c = 0; c < 2; ++c) {
                    const int pe = c * 4 + lg;
                    f16x8 A0 = *(const f16x8*)(sb + (px0 << 7) + ((pe ^ (px0 & 7)) << 4));
                    f16x8 A1 = *(const f16x8*)(sb + (px1 << 7) + ((pe ^ (px1 & 7)) << 4));
                    f16x8 A2 = *(const f16x8*)(sb + (px2 << 7) + ((pe ^ (px2 & 7)) << 4));
                    f16x8 A3 = *(const f16x8*)(sb + (px3 << 7) + ((pe ^ (px3 & 7)) << 4));
                    A0 = ok0 ? A0 : zf;
                    A3 = ok3 ? A3 : zf;
                    const f16x8 W0 = Wreg[k9][0][c];
                    const f16x8 W1 = Wreg[k9][1][c];
                    acc[0][0] = __builtin_amdgcn_mfma_f32_16x16x32_f16(W0, A0, acc[0][0], 0, 0, 0);
                    acc[0][1] = __builtin_amdgcn_mfma_f32_16x16x32_f16(W1, A0, acc[0][1], 0, 0, 0);
                    acc[1][0] = __builtin_amdgcn_mfma_f32_16x16x32_f16(W0, A1, acc[1][0], 0, 0, 0);
                    acc[1][1] = __builtin_amdgcn_mfma_f32_16x16x32_f16(W1, A1, acc[1][1], 0, 0, 0);
                    acc[2][0] = __builtin_amdgcn_mfma_f32_16x16x32_f16(W0, A2, acc[2][0], 0, 0, 0);
                    acc[2][1] = __builtin_amdgcn_mfma_f32_16x16x32_f16(W1, A2, acc[2][1], 0, 0, 0);
                    acc[3][0] = __builtin_amdgcn_mfma_f32_16x16x32_f16(W0, A3, acc[3][0], 0, 0, 0);
                    acc[3][1] = __builtin_amdgcn_mfma_f32_16x16x32_f16(W1, A3, acc[3][1], 0, 0, 0);
                }
            }
        }

        const size_t rb = (img + y) * 256;       // exactly 8 stores per wave
#pragma unroll
        for (int m = 0; m < 4; ++m) {
            f16* ap = act + (rb + pg * 64 + m * 16 + lr) * 64 + cg * 32 + lg * 4;
#pragma unroll
            for (int n = 0; n < 2; ++n) {
                f16x4 o;
#pragma unroll
                for (int q = 0; q < 4; ++q) {
                    float v = acc[m][n][q] + bias[n][q];
                    v = v / (1.f + __expf(-v));
                    o[q] = (f16)v;
                }
                *reinterpret_cast<f16x4*>(ap + n * 16) = o;
            }
        }
        if (r < 3) {
            asm volatile("s_barrier" ::: "memory");
            __builtin_amdgcn_sched_barrier(0);
        }
    }
}

// K2 v2: conv2 via packed f16 dot2 (4x fewer VALU ops) + XCD swizzle.
__global__ __launch_bounds__(256) void k_conv2(
        const f16* __restrict__ act, const float* __restrict__ w2,
        const f16* __restrict__ w2t,
        const float* __restrict__ b2, const float* __restrict__ dtp,
        float* __restrict__ psi) {
    const int bid = blockIdx.x;                  // 0..1023
    const int swz = (bid & 7) * 128 + (bid >> 3);
    const int bx = swz & 7, by = (swz >> 3) & 31, b = swz >> 8;
    const int tx = threadIdx.x & 31, ty = threadIdx.x >> 5;
    const int px = bx * 32 + tx;
    const int py = by * 8 + ty;

    float a0 = 0.f, a1 = 0.f, a2 = 0.f, a3 = 0.f;
#pragma unroll
    for (int dy = -1; dy <= 1; ++dy) {
        const int yy = py + dy;
        if ((unsigned)yy >= (unsigned)H) continue;
#pragma unroll
        for (int dx = -1; dx <= 1; ++dx) {
            const int xx = px + dx;
            const int k9 = (dy + 1) * 3 + (dx + 1);
            if ((unsigned)xx < (unsigned)W) {
                const f16x8* ap = reinterpret_cast<const f16x8*>(
                    act + (((size_t)b * H + yy) * W + xx) * 64);
#if __has_builtin(__builtin_amdgcn_fdot2)
                const f16* wp = w2t + k9 * 64;
#pragma unroll
                for (int g = 0; g < 8; ++g) {
                    const f16x8 v = ap[g];
                    const f16* wq = wp + g * 8;
                    a0 = __builtin_amdgcn_fdot2((f16x2){v[0], v[1]},
                         *(const f16x2*)(wq + 0), a0, false);
                    a1 = __builtin_amdgcn_fdot2((f16x2){v[2], v[3]},
                         *(const f16x2*)(wq + 2), a1, false);
                    a2 = __builtin_amdgcn_fdot2((f16x2){v[4], v[5]},
                         *(const f16x2*)(wq + 4), a2, false);
                    a3 = __builtin_amdgcn_fdot2((f16x2){v[6], v[7]},
                         *(const f16x2*)(wq + 6), a3, false);
                }
#else
                const float* wp = w2 + k9;
#pragma unroll
                for (int g = 0; g < 8; ++g) {
                    const f16x8 v = ap[g];
                    const int cb = g * 8;
                    a0 = fmaf((float)v[0], wp[(cb + 0) * 9], a0);
                    a1 = fmaf((float)v[1], wp[(cb + 1) * 9], a1);
                    a2 = fmaf((float)v[2], wp[(cb + 2) * 9], a2);
                    a3 = fmaf((float)v[3], wp[(cb + 3) * 9], a3);
                    a0 = fmaf((float)v[4], wp[(cb + 4) * 9], a0);
                    a1 = fmaf((float)v[5], wp[(cb + 5) * 9], a1);
                    a2 = fmaf((float)v[6], wp[(cb + 6) * 9], a2);
                    a3 = fmaf((float)v[7], wp[(cb + 7) * 9], a3);
                }
#endif
            }
        }
    }
    psi[((size_t)b * H + py) * W + px] = ((a0 + a1) + (a2 + a3) + b2[0]) * dtp[0];
}

// K3 v3: block = 1 row-half (128 px) x ALL 128 channels (proven R8/R11).
__global__ __launch_bounds__(256, 4) void k_sample3(
        const f16* __restrict__ Xt_r, const f16* __restrict__ Xt_i,
        const float* __restrict__ psi, float* __restrict__ out) {
    __shared__ int   s_off[4][128];
    __shared__ float s_w[4][128];
    __shared__ __align__(16) float s_stage[64][132];

    const int tid = threadIdx.x;
    const int bid = blockIdx.x;
    const int swz = (bid & 7) * 256 + (bid >> 3);
    const int seg = swz & 1, y = (swz >> 1) & 255, b = swz >> 9;
    const int x0 = seg * 128;

    if (tid < 128) {
        const int px = x0 + tid;
        const float* pb = psi + b * HWp;
        const int yp = min(y + 1, H - 1), ym = max(y - 1, 0);
        const int xp = min(px + 1, W - 1), xm = max(px - 1, 0);
        const float u = 0.5f * (pb[yp * W + px] - pb[ym * W + px]);
        const float v = -0.5f * (pb[y * W + xp] - pb[y * W + xm]);
        const float gx = (-1.f + 2.f * px / (float)(W - 1)) - u * (2.f / (float)W);
        const float gy = (-1.f + 2.f * y / (float)(H - 1)) - v * (2.f / (float)H);
        float ix = fminf(fmaxf((gx + 1.f) * 0.5f * (float)(W - 1), 0.f), (float)(W - 1));
        float iy = fminf(fmaxf((gy + 1.f) * 0.5f * (float)(H - 1), 0.f), (float)(H - 1));
        const float xf = floorf(ix), yf = floorf(iy);
        const float wx = ix - xf, wy = iy - yf;
        const int ix0 = (int)xf, iy0 = (int)yf;
        const int ix1 = min(ix0 + 1, W - 1), iy1 = min(iy0 + 1, H - 1);
        s_off[0][tid] = (iy0 * W + ix0) * 128;
        s_off[1][tid] = (iy0 * W + ix1) * 128;
        s_off[2][tid] = (iy1 * W + ix0) * 128;
        s_off[3][tid] = (iy1 * W + ix1) * 128;
        s_w[0][tid] = (1.f - wx) * (1.f - wy);
        s_w[1][tid] = wx * (1.f - wy);
        s_w[2][tid] = (1.f - wx) * wy;
        s_w[3][tid] = wx * wy;
    }
    __syncthreads();

    const int p = tid >> 1, s = tid & 1;
    const int o0 = s_off[0][p], o1 = s_off[1][p], o2 = s_off[2][p], o3 = s_off[3][p];
    const float w0 = s_w[0][p], w1 = s_w[1][p], w2 = s_w[2][p], w3 = s_w[3][p];
    const int cl = tid >> 5;
    const int pxq = (tid & 31) * 4;
    const size_t obase = (size_t)b * 128 * HWp + (size_t)y * W + x0 + pxq;

#pragma unroll
    for (int pl = 0; pl < 2; ++pl) {
        const char* base = (const char*)(pl ? Xt_i : Xt_r)
                         + (size_t)b * HWp * 128 + s * 64;
        const char* c0 = base + o0;
        const char* c1 = base + o1;
        const char* c2 = base + o2;
        const char* c3 = base + o3;
        f16x8 h00 = *(const f16x8*)(c0);      f16x8 h01 = *(const f16x8*)(c0 + 16);
        f16x8 h02 = *(const f16x8*)(c0 + 32); f16x8 h03 = *(const f16x8*)(c0 + 48);
        f16x8 h10 = *(const f16x8*)(c1);      f16x8 h11 = *(const f16x8*)(c1 + 16);
        f16x8 h12 = *(const f16x8*)(c1 + 32); f16x8 h13 = *(const f16x8*)(c1 + 48);
        f16x8 h20 = *(const f16x8*)(c2);      f16x8 h21 = *(const f16x8*)(c2 + 16);
        f16x8 h22 = *(const f16x8*)(c2 + 32); f16x8 h23 = *(const f16x8*)(c2 + 48);
        f16x8 h30 = *(const f16x8*)(c3);      f16x8 h31 = *(const f16x8*)(c3 + 16);
        f16x8 h32 = *(const f16x8*)(c3 + 32); f16x8 h33 = *(const f16x8*)(c3 + 48);

        const int rb = s << 5;
#pragma unroll
        for (int k = 0; k < 8; ++k) {
            s_stage[rb + k][p] = w0 * (float)h00[k] + w1 * (float)h10[k]
                               + w2 * (float)h20[k] + w3 * (float)h30[k];
            s_stage[rb + 8 + k][p] = w0 * (float)h01[k] + w1 * (float)h11[k]
                                   + w2 * (float)h21[k] + w3 * (float)h31[k];
            s_stage[rb + 16 + k][p] = w0 * (float)h02[k] + w1 * (float)h12[k]
                                    + w2 * (float)h22[k] + w3 * (float)h32[k];
            s_stage[rb + 24 + k][p] = w0 * (float)h03[k] + w1 * (float)h13[k]
                                    + w2 * (float)h23[k] + w3 * (float)h33[k];
        }
        __syncthreads();
#pragma unroll
        for (int k = 0; k < 8; ++k) {
            const int c = cl + (k << 3);
            f32x4 vv = *(const f32x4*)&s_stage[c][pxq];
            *(f32x4*)(out + obase + (size_t)(pl * 64 + c) * HWp) = vv;
        }
        __syncthreads();
    }
}

// K3 fallback: scalar gather from fp32 NCHW.
__global__ __launch_bounds__(256) void k_sample_fb(
        const float* __restrict__ zr, const float* __restrict__ zi,
        const float* __restrict__ psi, float* __restrict__ out) {
    const int tx = threadIdx.x & 31, ty = threadIdx.x >> 5;
    const int px = blockIdx.x * 32 + tx;
    const int py = blockIdx.y * 8 + ty;
    const int b  = blockIdx.z >> 3;
    const int c0 = (blockIdx.z & 7) * 16;

    const float* pb = psi + b * HWp;
    const int yp = min(py + 1, H - 1), ym = max(py - 1, 0);
    const int xp = min(px + 1, W - 1), xm = max(px - 1, 0);
    const float u = 0.5f * (pb[yp * W + px] - pb[ym * W + px]);
    const float v = -0.5f * (pb[py * W + xp] - pb[py * W + xm]);

    const float gx = (-1.f + 2.f * px / (float)(W - 1)) - u * (2.f / (float)W);
    const float gy = (-1.f + 2.f * py / (float)(H - 1)) - v * (2.f / (float)H);

    float ix = fminf(fmaxf((gx + 1.f) * 0.5f * (float)(W - 1), 0.f), (float)(W - 1));
    float iy = fminf(fmaxf((gy + 1.f) * 0.5f * (float)(H - 1), 0.f), (float)(H - 1));
    const float xf = floorf(ix), yf = floorf(iy);
    const float wx = ix - xf, wy = iy - yf;
    const int ix0 = (int)xf, iy0 = (int)yf;
    const int ix1 = min(ix0 + 1, W - 1), iy1 = min(iy0 + 1, H - 1);

    const int o00 = iy0 * W + ix0, o01 = iy0 * W + ix1;
    const int o10 = iy1 * W + ix0, o11 = iy1 * W + ix1;
    const float w00 = (1.f - wx) * (1.f - wy), w01 = wx * (1.f - wy);
    const float w10 = (1.f - wx) * wy, w11 = wx * wy;

    const float* src0 = (c0 < 64) ? (zr + (size_t)b * 64 * HWp + (size_t)c0 * HWp)
                                  : (zi + (size_t)b * 64 * HWp + (size_t)(c0 - 64) * HWp);
    float* ob = out + ((size_t)b * 128 + c0) * HWp + py * W + px;
#pragma unroll
    for (int c = 0; c < 16; ++c) {
        const float* p = src0 + (size_t)c * HWp;
        ob[(size_t)c * HWp] = p[o00] * w00 + p[o01] * w01 + p[o10] * w10 + p[o11] * w11;
    }
}

extern "C" void kernel_launch(void* const* d_in, const int* in_sizes, int n_in,
                              void* d_out, int out_size, void* d_ws, size_t ws_size,
                              hipStream_t stream) {
    const float* z_real = (const float*)d_in[0];
    const float* z_imag = (const float*)d_in[1];
    const float* dt     = (const float*)d_in[2];
    const float* w1     = (const float*)d_in[3];
    const float* b1     = (const float*)d_in[4];
    const float* w2     = (const float*)d_in[5];
    const float* b2     = (const float*)d_in[6];

    float* out = (float*)d_out;
    char* ws = (char*)d_ws;
    f16* w1tb = (f16*)ws;                       // 73728 B
    f16* w2t  = (f16*)(ws + WOFF2);             // 1152 B

    if (ws_size >= NEED_FAST) {
        // ws layout: w1tb | w2t | Xt_r | Xt_i | psi
        f16* Xt_r  = (f16*)(ws + WS0);
        f16* Xt_i  = (f16*)(ws + WS0 + PLANE);
        float* psi = (float*)(ws + WS0 + 2 * PLANE);
        f16* act   = (f16*)d_out;   // consumed by conv2 before sample3 overwrites

        hipLaunchKernelGGL(k_xt2, dim3(HWp / 64, 9), dim3(256), 0, stream,
                           z_real, z_imag, Xt_r, Xt_i, w1, w1tb, w2, w2t, 8);
        hipLaunchKernelGGL(k_conv1, dim3(256), dim3(512), 0, stream, Xt_r, w1tb, b1, act);
        hipLaunchKernelGGL(k_conv2, dim3(1024), dim3(256), 0, stream,
                           act, w2, w2t, b2, dt, psi);
        hipLaunchKernelGGL(k_sample3, dim3(2048), dim3(256), 0, stream,
                           Xt_r, Xt_i, psi, out);
    } else {
        float* psi = (float*)(ws + WS0);
        f16* Xt  = (f16*)((char*)d_out + 4096);
        f16* act = (f16*)((char*)d_out + 4096 + PLANE);

        hipLaunchKernelGGL(k_xt2, dim3(HWp / 64, 5), dim3(256), 0, stream,
                           z_real, z_real, Xt, Xt, w1, w1tb, w2, w2t, 4);
        hipLaunchKernelGGL(k_conv1, dim3(256), dim3(512), 0, stream, Xt, w1tb, b1, act);
        hipLaunchKernelGGL(k_conv2, dim3(1024), dim3(256), 0, stream,
                           act, w2, w2t, b2, dt, psi);
        hipLaunchKernelGGL(k_sample_fb, dim3(8, 32, 32), dim3(256), 0, stream,
                           z_real, z_imag, psi, out);
    }
}